// Round 1
// baseline (273.499 us; speedup 1.0000x reference)
//
#include <hip/hip_runtime.h>
#include <hip/hip_bf16.h>
#include <stdint.h>

typedef float f32x4 __attribute__((ext_vector_type(4)));
typedef short bf16x8 __attribute__((ext_vector_type(8)));

#define DEV static __device__ __forceinline__

DEV float bf2f(short u) {
  union { float f; unsigned i; } v;
  v.i = ((unsigned)(unsigned short)u) << 16;
  return v.f;
}
DEV short f2bf(float f) {
  union { float f; unsigned i; } v;
  v.f = f;
  unsigned lsb = (v.i >> 16) & 1u;
  v.i += 0x7fffu + lsb;
  return (short)(v.i >> 16);
}

DEV void glds16(const void* g, void* l) {
  __builtin_amdgcn_global_load_lds(
      (const __attribute__((address_space(1))) void*)g,
      (__attribute__((address_space(3))) void*)l, 16, 0, 0);
}

// ---------------------------------------------------------------------------
// Convert fp32 -> bf16 hi/lo splits (x, y, Wq, Wk) and bf16 (Wv, Wo)
// ---------------------------------------------------------------------------
__global__ __launch_bounds__(256) void k_convert(
    const float* __restrict__ x, const float* __restrict__ y,
    const float* __restrict__ wq, const float* __restrict__ wk,
    const float* __restrict__ wv, const float* __restrict__ wo,
    short* __restrict__ xhi, short* __restrict__ xlo,
    short* __restrict__ yhi, short* __restrict__ ylo,
    short* __restrict__ wqhi, short* __restrict__ wqlo,
    short* __restrict__ wkhi, short* __restrict__ wklo,
    short* __restrict__ wvhi, short* __restrict__ wohi) {
  const float* src; short* hi; short* lo; int n;
  switch (blockIdx.y) {
    case 0: src = x;  hi = xhi;  lo = xlo;    n = 4194304; break;
    case 1: src = y;  hi = yhi;  lo = ylo;    n = 4194304; break;
    case 2: src = wq; hi = wqhi; lo = wqlo;   n = 1048576; break;
    case 3: src = wk; hi = wkhi; lo = wklo;   n = 1048576; break;
    case 4: src = wv; hi = wvhi; lo = nullptr; n = 1048576; break;
    default: src = wo; hi = wohi; lo = nullptr; n = 1048576; break;
  }
  int i4 = blockIdx.x * 256 + threadIdx.x;
  if (i4 * 4 >= n) return;
  float4 v = ((const float4*)src)[i4];
  short4 h, l;
  float* pv = (float*)&v;
  short* ph = (short*)&h;
  short* pl = (short*)&l;
#pragma unroll
  for (int e = 0; e < 4; ++e) {
    short hh = f2bf(pv[e]);
    ph[e] = hh;
    pl[e] = f2bf(pv[e] - bf2f(hh));
  }
  ((short4*)hi)[i4] = h;
  if (lo) ((short4*)lo)[i4] = l;
}

// ---------------------------------------------------------------------------
// Plain bf16 NT GEMM with bias: C[i,j] = sum_k A[i,k]*B[j,k] + bias[j]
// tile 128x128, BK=64, 4 waves, source-swizzled global_load_lds staging
// ---------------------------------------------------------------------------
template <int OUT_F32>
__global__ __launch_bounds__(256) void k_gemm_plain(
    const short* __restrict__ A, const short* __restrict__ B,
    const float* __restrict__ bias, void* __restrict__ C, int M, int N, int K) {
  __shared__ __align__(16) short As[128 * 64];
  __shared__ __align__(16) short Bs[128 * 64];
  const int tid = threadIdx.x, lane = tid & 63;
  const int w = tid >> 6, wr = w >> 1, wc = w & 1;
  const int lo = lane & 15, hi4 = lane >> 4;
  const long bRow = (long)blockIdx.y * 128;
  const long bCol = (long)blockIdx.x * 128;
  f32x4 acc[4][4] = {};
  const int nks = K >> 6;
  for (int ks = 0; ks < nks; ++ks) {
#pragma unroll
    for (int i = 0; i < 4; ++i) {
      int c = i * 256 + tid;
      int r = c >> 3;
      int wi = ((c & 7) * 16) ^ ((r & 7) << 4);
      glds16((const char*)A + (bRow + r) * (long)(K * 2) + ks * 128 + wi, (char*)As + c * 16);
    }
#pragma unroll
    for (int i = 0; i < 4; ++i) {
      int c = i * 256 + tid;
      int r = c >> 3;
      int wi = ((c & 7) * 16) ^ ((r & 7) << 4);
      glds16((const char*)B + (bCol + r) * (long)(K * 2) + ks * 128 + wi, (char*)Bs + c * 16);
    }
    __syncthreads();
#pragma unroll
    for (int kk = 0; kk < 2; ++kk) {
      bf16x8 af[4], bfr[4];
#pragma unroll
      for (int m = 0; m < 4; ++m) {
        int r = wr * 64 + m * 16 + lo;
        af[m] = *(const bf16x8*)((const char*)As + r * 128 + ((kk * 64 + hi4 * 16) ^ ((r & 7) << 4)));
      }
#pragma unroll
      for (int n = 0; n < 4; ++n) {
        int r = wc * 64 + n * 16 + lo;
        bfr[n] = *(const bf16x8*)((const char*)Bs + r * 128 + ((kk * 64 + hi4 * 16) ^ ((r & 7) << 4)));
      }
#pragma unroll
      for (int m = 0; m < 4; ++m)
#pragma unroll
        for (int n = 0; n < 4; ++n)
          acc[m][n] = __builtin_amdgcn_mfma_f32_16x16x32_bf16(af[m], bfr[n], acc[m][n], 0, 0, 0);
    }
    __syncthreads();
  }
#pragma unroll
  for (int n = 0; n < 4; ++n) {
    long col = bCol + wc * 64 + n * 16 + lo;
    float bv = bias[col];
#pragma unroll
    for (int m = 0; m < 4; ++m)
#pragma unroll
      for (int j = 0; j < 4; ++j) {
        long row = bRow + wr * 64 + m * 16 + hi4 * 4 + j;
        float v = acc[m][n][j] + bv;
        if (OUT_F32) ((float*)C)[row * N + col] = v;
        else ((short*)C)[row * N + col] = f2bf(v);
      }
  }
}

// ---------------------------------------------------------------------------
// Split-precision NT GEMM: C = (Ahi+Alo)(Bhi+Blo)^T + bias  (3-term MFMA)
// tile 128x64, BK=64, 4 waves (each 32 rows x 64 cols), outputs hi/lo bf16
// ---------------------------------------------------------------------------
__global__ __launch_bounds__(256) void k_gemm_split(
    const short* __restrict__ Ahi, const short* __restrict__ Alo,
    const short* __restrict__ Bhi, const short* __restrict__ Blo,
    const float* __restrict__ bias, short* __restrict__ Chi,
    short* __restrict__ Clo, int M, int N, int K) {
  __shared__ __align__(16) short AsH[128 * 64], AsL[128 * 64];
  __shared__ __align__(16) short BsH[64 * 64], BsL[64 * 64];
  const int tid = threadIdx.x, lane = tid & 63;
  const int w = tid >> 6;  // 4 waves = 4 row quadrants of 32
  const int lo = lane & 15, hi4 = lane >> 4;
  const long bRow = (long)blockIdx.y * 128;
  const long bCol = (long)blockIdx.x * 64;
  f32x4 acc[2][4] = {};
  const int nks = K >> 6;
  for (int ks = 0; ks < nks; ++ks) {
#pragma unroll
    for (int i = 0; i < 4; ++i) {
      int c = i * 256 + tid;
      int r = c >> 3;
      int wi = ((c & 7) * 16) ^ ((r & 7) << 4);
      glds16((const char*)Ahi + (bRow + r) * (long)(K * 2) + ks * 128 + wi, (char*)AsH + c * 16);
      glds16((const char*)Alo + (bRow + r) * (long)(K * 2) + ks * 128 + wi, (char*)AsL + c * 16);
    }
#pragma unroll
    for (int i = 0; i < 2; ++i) {
      int c = i * 256 + tid;
      int r = c >> 3;
      int wi = ((c & 7) * 16) ^ ((r & 7) << 4);
      glds16((const char*)Bhi + (bCol + r) * (long)(K * 2) + ks * 128 + wi, (char*)BsH + c * 16);
      glds16((const char*)Blo + (bCol + r) * (long)(K * 2) + ks * 128 + wi, (char*)BsL + c * 16);
    }
    __syncthreads();
#pragma unroll
    for (int kk = 0; kk < 2; ++kk) {
      bf16x8 ah[2], al[2], bh[4], bl[4];
#pragma unroll
      for (int m = 0; m < 2; ++m) {
        int r = w * 32 + m * 16 + lo;
        int off = r * 128 + ((kk * 64 + hi4 * 16) ^ ((r & 7) << 4));
        ah[m] = *(const bf16x8*)((const char*)AsH + off);
        al[m] = *(const bf16x8*)((const char*)AsL + off);
      }
#pragma unroll
      for (int n = 0; n < 4; ++n) {
        int r = n * 16 + lo;
        int off = r * 128 + ((kk * 64 + hi4 * 16) ^ ((r & 7) << 4));
        bh[n] = *(const bf16x8*)((const char*)BsH + off);
        bl[n] = *(const bf16x8*)((const char*)BsL + off);
      }
#pragma unroll
      for (int m = 0; m < 2; ++m)
#pragma unroll
        for (int n = 0; n < 4; ++n) {
          acc[m][n] = __builtin_amdgcn_mfma_f32_16x16x32_bf16(ah[m], bh[n], acc[m][n], 0, 0, 0);
          acc[m][n] = __builtin_amdgcn_mfma_f32_16x16x32_bf16(ah[m], bl[n], acc[m][n], 0, 0, 0);
          acc[m][n] = __builtin_amdgcn_mfma_f32_16x16x32_bf16(al[m], bh[n], acc[m][n], 0, 0, 0);
        }
    }
    __syncthreads();
  }
#pragma unroll
  for (int n = 0; n < 4; ++n) {
    long col = bCol + n * 16 + lo;
    float bv = bias[col];
#pragma unroll
    for (int m = 0; m < 2; ++m)
#pragma unroll
      for (int j = 0; j < 4; ++j) {
        long row = bRow + w * 32 + m * 16 + hi4 * 4 + j;
        float v = acc[m][n][j] + bv;
        short h = f2bf(v);
        float res = v - bf2f(h);
        Chi[row * N + col] = h;
        Clo[row * N + col] = f2bf(res);
      }
  }
}

// ---------------------------------------------------------------------------
// Transpose V slices: Vb [g][1024 t][64 d] -> Vt [g][64 d][1024 t]
// ---------------------------------------------------------------------------
__global__ __launch_bounds__(256) void k_transpose_v(const short* __restrict__ Vb,
                                                     short* __restrict__ Vt) {
  __shared__ __align__(16) short T[64][264];
  int g = blockIdx.y, t0 = blockIdx.x * 256;
  int tid = threadIdx.x;
  const short* src = Vb + (long)g * 65536;
#pragma unroll
  for (int i = 0; i < 8; ++i) {
    int c = i * 256 + tid;  // 0..2047
    int t = c >> 3, dc = (c & 7) * 8;
    bf16x8 v = *(const bf16x8*)(src + (long)(t0 + t) * 64 + dc);
#pragma unroll
    for (int e = 0; e < 8; ++e) T[dc + e][t] = v[e];
  }
  __syncthreads();
  short* dst = Vt + (long)g * 65536;
#pragma unroll
  for (int i = 0; i < 8; ++i) {
    int c = i * 256 + tid;
    int d = c >> 5, tc = (c & 31) * 8;
    bf16x8 v = *(const bf16x8*)(&T[d][tc]);
    *(bf16x8*)(dst + (long)d * 1024 + t0 + tc) = v;
  }
}

// ---------------------------------------------------------------------------
// Pass A: per slice, L[t] = sum_s exp(S[s,t]);  Mu[s] = sum_t S[s,t]
// S via 3-term split MFMA. Block = 64 rows of one slice, 16 t-tiles of 64.
// ---------------------------------------------------------------------------
__global__ __launch_bounds__(256) void k_passA(
    const short* __restrict__ Qhi, const short* __restrict__ Qlo,
    const short* __restrict__ Khi, const short* __restrict__ Klo,
    float* __restrict__ L, float* __restrict__ Mu) {
  __shared__ __align__(16) short QsH[64 * 64], QsL[64 * 64], KsH[64 * 64], KsL[64 * 64];
  const int g = blockIdx.y, rb = blockIdx.x;
  const int tid = threadIdx.x, lane = tid & 63;
  const int w = tid >> 6, wr = w >> 1, wc = w & 1;
  const int lo = lane & 15, hi4 = lane >> 4;
  const long gbase = (long)g * 131072;  // bytes
#pragma unroll
  for (int i = 0; i < 2; ++i) {
    int c = i * 256 + tid;
    int r = c >> 3;
    int wi = ((c & 7) * 16) ^ ((r & 7) << 4);
    glds16((const char*)Qhi + gbase + (long)(rb * 64 + r) * 128 + wi, (char*)QsH + c * 16);
    glds16((const char*)Qlo + gbase + (long)(rb * 64 + r) * 128 + wi, (char*)QsL + c * 16);
  }
  float rowsum[2][4] = {};
  bf16x8 qh[2][2], ql[2][2];
  for (int tb = 0; tb < 16; ++tb) {
#pragma unroll
    for (int i = 0; i < 2; ++i) {
      int c = i * 256 + tid;
      int r = c >> 3;
      int wi = ((c & 7) * 16) ^ ((r & 7) << 4);
      glds16((const char*)Khi + gbase + (long)(tb * 64 + r) * 128 + wi, (char*)KsH + c * 16);
      glds16((const char*)Klo + gbase + (long)(tb * 64 + r) * 128 + wi, (char*)KsL + c * 16);
    }
    __syncthreads();
    if (tb == 0) {
#pragma unroll
      for (int kk = 0; kk < 2; ++kk)
#pragma unroll
        for (int m = 0; m < 2; ++m) {
          int r = wr * 32 + m * 16 + lo;
          int off = r * 128 + ((kk * 64 + hi4 * 16) ^ ((r & 7) << 4));
          qh[kk][m] = *(const bf16x8*)((const char*)QsH + off);
          ql[kk][m] = *(const bf16x8*)((const char*)QsL + off);
        }
    }
    f32x4 s[2][2] = {};
#pragma unroll
    for (int kk = 0; kk < 2; ++kk) {
      bf16x8 kh[2], kl[2];
#pragma unroll
      for (int n = 0; n < 2; ++n) {
        int r = wc * 32 + n * 16 + lo;
        int off = r * 128 + ((kk * 64 + hi4 * 16) ^ ((r & 7) << 4));
        kh[n] = *(const bf16x8*)((const char*)KsH + off);
        kl[n] = *(const bf16x8*)((const char*)KsL + off);
      }
#pragma unroll
      for (int m = 0; m < 2; ++m)
#pragma unroll
        for (int n = 0; n < 2; ++n) {
          s[m][n] = __builtin_amdgcn_mfma_f32_16x16x32_bf16(qh[kk][m], kh[n], s[m][n], 0, 0, 0);
          s[m][n] = __builtin_amdgcn_mfma_f32_16x16x32_bf16(qh[kk][m], kl[n], s[m][n], 0, 0, 0);
          s[m][n] = __builtin_amdgcn_mfma_f32_16x16x32_bf16(ql[kk][m], kh[n], s[m][n], 0, 0, 0);
        }
    }
#pragma unroll
    for (int n = 0; n < 2; ++n) {
      float cs = 0.f;
#pragma unroll
      for (int m = 0; m < 2; ++m)
#pragma unroll
        for (int j = 0; j < 4; ++j) {
          float sv = s[m][n][j] * 0.03125f;
          rowsum[m][j] += sv;
          cs += __expf(sv);
        }
      cs += __shfl_xor(cs, 16);
      cs += __shfl_xor(cs, 32);
      if (hi4 == 0) atomicAdd(&L[g * 1024 + tb * 64 + wc * 32 + n * 16 + lo], cs);
    }
    __syncthreads();
  }
#pragma unroll
  for (int m = 0; m < 2; ++m)
#pragma unroll
    for (int j = 0; j < 4; ++j) {
      float v = rowsum[m][j];
      v += __shfl_xor(v, 1);
      v += __shfl_xor(v, 2);
      v += __shfl_xor(v, 4);
      v += __shfl_xor(v, 8);
      if (lo == 0) atomicAdd(&Mu[g * 1024 + rb * 64 + wr * 32 + m * 16 + hi4 * 4 + j], v);
    }
}

// ---------------------------------------------------------------------------
// Pass B: recompute S (split), P1 = e/L, P2 = mask*e, PV both branches,
// out_pre = 0.5*(O1/R + O2/Z), bf16.
// ---------------------------------------------------------------------------
__global__ __launch_bounds__(256) void k_passB(
    const short* __restrict__ Qhi, const short* __restrict__ Qlo,
    const short* __restrict__ Khi, const short* __restrict__ Klo,
    const short* __restrict__ Vt, const float* __restrict__ L,
    const float* __restrict__ Mu, short* __restrict__ Pre,
    const int* __restrict__ rmask) {
  __shared__ __align__(16) short QsH[64 * 64], QsL[64 * 64], KsH[64 * 64], KsL[64 * 64];
  __shared__ __align__(16) short Vs[64 * 64];
  __shared__ __align__(16) short Ps[64 * 64];
  __shared__ float Rl[64], Zl[64];
  const int g = blockIdx.y, rb = blockIdx.x;
  const int tid = threadIdx.x, lane = tid & 63;
  const int w = tid >> 6, wr = w >> 1, wc = w & 1;
  const int lo = lane & 15, hi4 = lane >> 4;
  const long gbase = (long)g * 131072;
  const bool use_mask = (*rmask != 0);
  if (tid < 64) { Rl[tid] = 0.f; Zl[tid] = 0.f; }
#pragma unroll
  for (int i = 0; i < 2; ++i) {
    int c = i * 256 + tid;
    int r = c >> 3;
    int wi = ((c & 7) * 16) ^ ((r & 7) << 4);
    glds16((const char*)Qhi + gbase + (long)(rb * 64 + r) * 128 + wi, (char*)QsH + c * 16);
    glds16((const char*)Qlo + gbase + (long)(rb * 64 + r) * 128 + wi, (char*)QsL + c * 16);
  }
  float thre[2][4];
#pragma unroll
  for (int m = 0; m < 2; ++m)
#pragma unroll
    for (int j = 0; j < 4; ++j)
      thre[m][j] = Mu[g * 1024 + rb * 64 + wr * 32 + m * 16 + hi4 * 4 + j] * (1.f / 1024.f);
  float rpart[2][4] = {}, zpart[2][4] = {};
  f32x4 o1[4] = {}, o2[4] = {};
  bf16x8 qh[2][2], ql[2][2];

  for (int tb = 0; tb < 16; ++tb) {
#pragma unroll
    for (int i = 0; i < 2; ++i) {
      int c = i * 256 + tid;
      int r = c >> 3;
      int wi = ((c & 7) * 16) ^ ((r & 7) << 4);
      glds16((const char*)Khi + gbase + (long)(tb * 64 + r) * 128 + wi, (char*)KsH + c * 16);
      glds16((const char*)Klo + gbase + (long)(tb * 64 + r) * 128 + wi, (char*)KsL + c * 16);
      glds16((const char*)Vt + gbase + (long)r * 2048 + tb * 128 + wi, (char*)Vs + c * 16);
    }
    __syncthreads();
    if (tb == 0) {
#pragma unroll
      for (int kk = 0; kk < 2; ++kk)
#pragma unroll
        for (int m = 0; m < 2; ++m) {
          int r = wr * 32 + m * 16 + lo;
          int off = r * 128 + ((kk * 64 + hi4 * 16) ^ ((r & 7) << 4));
          qh[kk][m] = *(const bf16x8*)((const char*)QsH + off);
          ql[kk][m] = *(const bf16x8*)((const char*)QsL + off);
        }
    }
    f32x4 s[2][2] = {};
#pragma unroll
    for (int kk = 0; kk < 2; ++kk) {
      bf16x8 kh[2], kl[2];
#pragma unroll
      for (int n = 0; n < 2; ++n) {
        int r = wc * 32 + n * 16 + lo;
        int off = r * 128 + ((kk * 64 + hi4 * 16) ^ ((r & 7) << 4));
        kh[n] = *(const bf16x8*)((const char*)KsH + off);
        kl[n] = *(const bf16x8*)((const char*)KsL + off);
      }
#pragma unroll
      for (int m = 0; m < 2; ++m)
#pragma unroll
        for (int n = 0; n < 2; ++n) {
          s[m][n] = __builtin_amdgcn_mfma_f32_16x16x32_bf16(qh[kk][m], kh[n], s[m][n], 0, 0, 0);
          s[m][n] = __builtin_amdgcn_mfma_f32_16x16x32_bf16(qh[kk][m], kl[n], s[m][n], 0, 0, 0);
          s[m][n] = __builtin_amdgcn_mfma_f32_16x16x32_bf16(ql[kk][m], kh[n], s[m][n], 0, 0, 0);
        }
    }
    float Lv[2];
#pragma unroll
    for (int n = 0; n < 2; ++n) Lv[n] = L[g * 1024 + tb * 64 + wc * 32 + n * 16 + lo];
#pragma unroll
    for (int m = 0; m < 2; ++m)
#pragma unroll
      for (int n = 0; n < 2; ++n)
#pragma unroll
        for (int j = 0; j < 4; ++j) {
          float sv = s[m][n][j] * 0.03125f;
          float e = __expf(sv);
          float p1 = e / Lv[n];
          rpart[m][j] += p1;
          float p2 = (!use_mask || (sv > thre[m][j])) ? e : 0.f;
          zpart[m][j] += p2;
          int row = wr * 32 + m * 16 + hi4 * 4 + j;
          int colb = (wc * 32 + n * 16 + lo) * 2;
          *(short*)((char*)Ps + row * 128 + (colb ^ ((row & 7) << 4))) = f2bf(p1);
          s[m][n][j] = p2;
        }
    __syncthreads();
    {
      int prow = w * 16 + lo;
#pragma unroll
      for (int kk = 0; kk < 2; ++kk) {
        bf16x8 pa = *(const bf16x8*)((const char*)Ps + prow * 128 +
                                     ((kk * 64 + hi4 * 16) ^ ((prow & 7) << 4)));
#pragma unroll
        for (int n = 0; n < 4; ++n) {
          int d = n * 16 + lo;
          bf16x8 vb = *(const bf16x8*)((const char*)Vs + d * 128 +
                                       ((kk * 64 + hi4 * 16) ^ ((d & 7) << 4)));
          o1[n] = __builtin_amdgcn_mfma_f32_16x16x32_bf16(pa, vb, o1[n], 0, 0, 0);
        }
      }
    }
    __syncthreads();
#pragma unroll
    for (int m = 0; m < 2; ++m)
#pragma unroll
      for (int n = 0; n < 2; ++n)
#pragma unroll
        for (int j = 0; j < 4; ++j) {
          int row = wr * 32 + m * 16 + hi4 * 4 + j;
          int colb = (wc * 32 + n * 16 + lo) * 2;
          *(short*)((char*)Ps + row * 128 + (colb ^ ((row & 7) << 4))) = f2bf(s[m][n][j]);
        }
    __syncthreads();
    {
      int prow = w * 16 + lo;
#pragma unroll
      for (int kk = 0; kk < 2; ++kk) {
        bf16x8 pa = *(const bf16x8*)((const char*)Ps + prow * 128 +
                                     ((kk * 64 + hi4 * 16) ^ ((prow & 7) << 4)));
#pragma unroll
        for (int n = 0; n < 4; ++n) {
          int d = n * 16 + lo;
          bf16x8 vb = *(const bf16x8*)((const char*)Vs + d * 128 +
                                       ((kk * 64 + hi4 * 16) ^ ((d & 7) << 4)));
          o2[n] = __builtin_amdgcn_mfma_f32_16x16x32_bf16(pa, vb, o2[n], 0, 0, 0);
        }
      }
    }
    __syncthreads();
  }
#pragma unroll
  for (int m = 0; m < 2; ++m)
#pragma unroll
    for (int j = 0; j < 4; ++j) {
      float r = rpart[m][j], z = zpart[m][j];
      r += __shfl_xor(r, 1); r += __shfl_xor(r, 2); r += __shfl_xor(r, 4); r += __shfl_xor(r, 8);
      z += __shfl_xor(z, 1); z += __shfl_xor(z, 2); z += __shfl_xor(z, 4); z += __shfl_xor(z, 8);
      if (lo == 0) {
        atomicAdd(&Rl[wr * 32 + m * 16 + hi4 * 4 + j], r);
        atomicAdd(&Zl[wr * 32 + m * 16 + hi4 * 4 + j], z);
      }
    }
  __syncthreads();
#pragma unroll
  for (int n = 0; n < 4; ++n)
#pragma unroll
    for (int j = 0; j < 4; ++j) {
      int rl = w * 16 + hi4 * 4 + j;
      float r = fmaxf(Rl[rl], 1e-12f);
      float z = fmaxf(Zl[rl], 1e-30f);
      float val = 0.5f * (o1[n][j] / r + o2[n][j] / z);
      Pre[(long)g * 65536 + (long)(rb * 64 + rl) * 64 + n * 16 + lo] = f2bf(val);
    }
}

// ---------------------------------------------------------------------------
extern "C" void kernel_launch(void* const* d_in, const int* in_sizes, int n_in,
                              void* d_out, int out_size, void* d_ws, size_t ws_size,
                              hipStream_t stream) {
  const float* x  = (const float*)d_in[0];
  const float* y  = (const float*)d_in[1];
  const float* Wq = (const float*)d_in[2];
  const float* bq = (const float*)d_in[3];
  const float* Wk = (const float*)d_in[4];
  const float* bk = (const float*)d_in[5];
  const float* Wv = (const float*)d_in[6];
  const float* bv = (const float*)d_in[7];
  const float* Wo = (const float*)d_in[8];
  const float* bo = (const float*)d_in[9];
  const int* rm   = (const int*)d_in[10];
  float* out = (float*)d_out;

  char* ws = (char*)d_ws;
  size_t off = 0;
  auto alloc = [&](size_t bytes) {
    char* p = ws + off;
    off += (bytes + 255) & ~(size_t)255;
    return p;
  };
  short* xhi  = (short*)alloc(4194304 * 2);
  short* xlo  = (short*)alloc(4194304 * 2);
  short* yhi  = (short*)alloc(4194304 * 2);
  short* ylo  = (short*)alloc(4194304 * 2);
  short* wqhi = (short*)alloc(1048576 * 2);
  short* wqlo = (short*)alloc(1048576 * 2);
  short* wkhi = (short*)alloc(1048576 * 2);
  short* wklo = (short*)alloc(1048576 * 2);
  short* wvhi = (short*)alloc(1048576 * 2);
  short* wohi = (short*)alloc(1048576 * 2);
  short* QhiB = (short*)alloc(4194304 * 2);
  short* QloB = (short*)alloc(4194304 * 2);
  short* KhiB = (short*)alloc(4194304 * 2);
  short* KloB = (short*)alloc(4194304 * 2);
  short* Vb   = (short*)alloc(4194304 * 2);
  short* VtB  = (short*)alloc(4194304 * 2);
  short* pre  = (short*)alloc(4194304 * 2);
  float* L    = (float*)alloc(65536 * 4);
  float* Mu   = (float*)alloc(65536 * 4);
  if (off > ws_size) return;  // workspace too small; fail loudly via validation

  hipMemsetAsync(L, 0, 2 * 65536 * 4, stream);  // L and Mu are contiguous

  k_convert<<<dim3(4096, 6), 256, 0, stream>>>(x, y, Wq, Wk, Wv, Wo, xhi, xlo, yhi, ylo,
                                               wqhi, wqlo, wkhi, wklo, wvhi, wohi);

  k_gemm_split<<<dim3(16, 32), 256, 0, stream>>>(xhi, xlo, wqhi, wqlo, bq, QhiB, QloB,
                                                 4096, 1024, 1024);
  k_gemm_split<<<dim3(16, 32), 256, 0, stream>>>(yhi, ylo, wkhi, wklo, bk, KhiB, KloB,
                                                 4096, 1024, 1024);
  k_gemm_plain<0><<<dim3(8, 32), 256, 0, stream>>>(yhi, wvhi, bv, Vb, 4096, 1024, 1024);
  k_transpose_v<<<dim3(4, 64), 256, 0, stream>>>(Vb, VtB);
  k_passA<<<dim3(16, 64), 256, 0, stream>>>(QhiB, QloB, KhiB, KloB, L, Mu);
  k_passB<<<dim3(16, 64), 256, 0, stream>>>(QhiB, QloB, KhiB, KloB, VtB, L, Mu, pre, rm);
  k_gemm_plain<1><<<dim3(8, 32), 256, 0, stream>>>(pre, wohi, bo, out, 4096, 1024, 1024);
}

// Round 2
// 254.841 us; speedup vs baseline: 1.0732x; 1.0732x over previous
//
#include <hip/hip_runtime.h>
#include <hip/hip_bf16.h>
#include <stdint.h>

typedef float f32x4 __attribute__((ext_vector_type(4)));
typedef short bf16x8 __attribute__((ext_vector_type(8)));

#define DEV static __device__ __forceinline__

DEV float bf2f(short u) {
  union { float f; unsigned i; } v;
  v.i = ((unsigned)(unsigned short)u) << 16;
  return v.f;
}
DEV short f2bf(float f) {
  union { float f; unsigned i; } v;
  v.f = f;
  unsigned lsb = (v.i >> 16) & 1u;
  v.i += 0x7fffu + lsb;
  return (short)(v.i >> 16);
}

DEV void glds16(const void* g, void* l) {
  __builtin_amdgcn_global_load_lds(
      (const __attribute__((address_space(1))) void*)g,
      (__attribute__((address_space(3))) void*)l, 16, 0, 0);
}

// ---------------------------------------------------------------------------
// Convert fp32 -> bf16 hi/lo splits (x, y, Wq, Wk) and bf16 (Wv, Wo)
// ---------------------------------------------------------------------------
__global__ __launch_bounds__(256) void k_convert(
    const float* __restrict__ x, const float* __restrict__ y,
    const float* __restrict__ wq, const float* __restrict__ wk,
    const float* __restrict__ wv, const float* __restrict__ wo,
    short* __restrict__ xhi, short* __restrict__ xlo,
    short* __restrict__ yhi, short* __restrict__ ylo,
    short* __restrict__ wqhi, short* __restrict__ wqlo,
    short* __restrict__ wkhi, short* __restrict__ wklo,
    short* __restrict__ wvhi, short* __restrict__ wohi) {
  const float* src; short* hi; short* lo; int n;
  switch (blockIdx.y) {
    case 0: src = x;  hi = xhi;  lo = xlo;    n = 4194304; break;
    case 1: src = y;  hi = yhi;  lo = ylo;    n = 4194304; break;
    case 2: src = wq; hi = wqhi; lo = wqlo;   n = 1048576; break;
    case 3: src = wk; hi = wkhi; lo = wklo;   n = 1048576; break;
    case 4: src = wv; hi = wvhi; lo = nullptr; n = 1048576; break;
    default: src = wo; hi = wohi; lo = nullptr; n = 1048576; break;
  }
  int i4 = blockIdx.x * 256 + threadIdx.x;
  if (i4 * 4 >= n) return;
  float4 v = ((const float4*)src)[i4];
  short4 h, l;
  float* pv = (float*)&v;
  short* ph = (short*)&h;
  short* pl = (short*)&l;
#pragma unroll
  for (int e = 0; e < 4; ++e) {
    short hh = f2bf(pv[e]);
    ph[e] = hh;
    pl[e] = f2bf(pv[e] - bf2f(hh));
  }
  ((short4*)hi)[i4] = h;
  if (lo) ((short4*)lo)[i4] = l;
}

// ---------------------------------------------------------------------------
// Plain bf16 NT GEMM with bias
// ---------------------------------------------------------------------------
template <int OUT_F32>
__global__ __launch_bounds__(256) void k_gemm_plain(
    const short* __restrict__ A, const short* __restrict__ B,
    const float* __restrict__ bias, void* __restrict__ C, int M, int N, int K) {
  __shared__ __align__(16) short As[128 * 64];
  __shared__ __align__(16) short Bs[128 * 64];
  const int tid = threadIdx.x, lane = tid & 63;
  const int w = tid >> 6, wr = w >> 1, wc = w & 1;
  const int lo = lane & 15, hi4 = lane >> 4;
  const long bRow = (long)blockIdx.y * 128;
  const long bCol = (long)blockIdx.x * 128;
  f32x4 acc[4][4] = {};
  const int nks = K >> 6;
  for (int ks = 0; ks < nks; ++ks) {
#pragma unroll
    for (int i = 0; i < 4; ++i) {
      int c = i * 256 + tid;
      int r = c >> 3;
      int wi = ((c & 7) * 16) ^ ((r & 7) << 4);
      glds16((const char*)A + (bRow + r) * (long)(K * 2) + ks * 128 + wi, (char*)As + c * 16);
    }
#pragma unroll
    for (int i = 0; i < 4; ++i) {
      int c = i * 256 + tid;
      int r = c >> 3;
      int wi = ((c & 7) * 16) ^ ((r & 7) << 4);
      glds16((const char*)B + (bCol + r) * (long)(K * 2) + ks * 128 + wi, (char*)Bs + c * 16);
    }
    __syncthreads();
#pragma unroll
    for (int kk = 0; kk < 2; ++kk) {
      bf16x8 af[4], bfr[4];
#pragma unroll
      for (int m = 0; m < 4; ++m) {
        int r = wr * 64 + m * 16 + lo;
        af[m] = *(const bf16x8*)((const char*)As + r * 128 + ((kk * 64 + hi4 * 16) ^ ((r & 7) << 4)));
      }
#pragma unroll
      for (int n = 0; n < 4; ++n) {
        int r = wc * 64 + n * 16 + lo;
        bfr[n] = *(const bf16x8*)((const char*)Bs + r * 128 + ((kk * 64 + hi4 * 16) ^ ((r & 7) << 4)));
      }
#pragma unroll
      for (int m = 0; m < 4; ++m)
#pragma unroll
        for (int n = 0; n < 4; ++n)
          acc[m][n] = __builtin_amdgcn_mfma_f32_16x16x32_bf16(af[m], bfr[n], acc[m][n], 0, 0, 0);
    }
    __syncthreads();
  }
#pragma unroll
  for (int n = 0; n < 4; ++n) {
    long col = bCol + wc * 64 + n * 16 + lo;
    float bv = bias[col];
#pragma unroll
    for (int m = 0; m < 4; ++m)
#pragma unroll
      for (int j = 0; j < 4; ++j) {
        long row = bRow + wr * 64 + m * 16 + hi4 * 4 + j;
        float v = acc[m][n][j] + bv;
        if (OUT_F32) ((float*)C)[row * N + col] = v;
        else ((short*)C)[row * N + col] = f2bf(v);
      }
  }
}

// ---------------------------------------------------------------------------
// Split-precision NT GEMM: C = (Ahi+Alo)(Bhi+Blo)^T + bias  (3-term MFMA)
// ---------------------------------------------------------------------------
__global__ __launch_bounds__(256) void k_gemm_split(
    const short* __restrict__ Ahi, const short* __restrict__ Alo,
    const short* __restrict__ Bhi, const short* __restrict__ Blo,
    const float* __restrict__ bias, short* __restrict__ Chi,
    short* __restrict__ Clo, int M, int N, int K) {
  __shared__ __align__(16) short AsH[128 * 64], AsL[128 * 64];
  __shared__ __align__(16) short BsH[64 * 64], BsL[64 * 64];
  const int tid = threadIdx.x, lane = tid & 63;
  const int w = tid >> 6;
  const int lo = lane & 15, hi4 = lane >> 4;
  const long bRow = (long)blockIdx.y * 128;
  const long bCol = (long)blockIdx.x * 64;
  f32x4 acc[2][4] = {};
  const int nks = K >> 6;
  for (int ks = 0; ks < nks; ++ks) {
#pragma unroll
    for (int i = 0; i < 4; ++i) {
      int c = i * 256 + tid;
      int r = c >> 3;
      int wi = ((c & 7) * 16) ^ ((r & 7) << 4);
      glds16((const char*)Ahi + (bRow + r) * (long)(K * 2) + ks * 128 + wi, (char*)AsH + c * 16);
      glds16((const char*)Alo + (bRow + r) * (long)(K * 2) + ks * 128 + wi, (char*)AsL + c * 16);
    }
#pragma unroll
    for (int i = 0; i < 2; ++i) {
      int c = i * 256 + tid;
      int r = c >> 3;
      int wi = ((c & 7) * 16) ^ ((r & 7) << 4);
      glds16((const char*)Bhi + (bCol + r) * (long)(K * 2) + ks * 128 + wi, (char*)BsH + c * 16);
      glds16((const char*)Blo + (bCol + r) * (long)(K * 2) + ks * 128 + wi, (char*)BsL + c * 16);
    }
    __syncthreads();
#pragma unroll
    for (int kk = 0; kk < 2; ++kk) {
      bf16x8 ah[2], al[2], bh[4], bl[4];
#pragma unroll
      for (int m = 0; m < 2; ++m) {
        int r = w * 32 + m * 16 + lo;
        int off = r * 128 + ((kk * 64 + hi4 * 16) ^ ((r & 7) << 4));
        ah[m] = *(const bf16x8*)((const char*)AsH + off);
        al[m] = *(const bf16x8*)((const char*)AsL + off);
      }
#pragma unroll
      for (int n = 0; n < 4; ++n) {
        int r = n * 16 + lo;
        int off = r * 128 + ((kk * 64 + hi4 * 16) ^ ((r & 7) << 4));
        bh[n] = *(const bf16x8*)((const char*)BsH + off);
        bl[n] = *(const bf16x8*)((const char*)BsL + off);
      }
#pragma unroll
      for (int m = 0; m < 2; ++m)
#pragma unroll
        for (int n = 0; n < 4; ++n) {
          acc[m][n] = __builtin_amdgcn_mfma_f32_16x16x32_bf16(ah[m], bh[n], acc[m][n], 0, 0, 0);
          acc[m][n] = __builtin_amdgcn_mfma_f32_16x16x32_bf16(ah[m], bl[n], acc[m][n], 0, 0, 0);
          acc[m][n] = __builtin_amdgcn_mfma_f32_16x16x32_bf16(al[m], bh[n], acc[m][n], 0, 0, 0);
        }
    }
    __syncthreads();
  }
#pragma unroll
  for (int n = 0; n < 4; ++n) {
    long col = bCol + n * 16 + lo;
    float bv = bias[col];
#pragma unroll
    for (int m = 0; m < 2; ++m)
#pragma unroll
      for (int j = 0; j < 4; ++j) {
        long row = bRow + w * 32 + m * 16 + hi4 * 4 + j;
        float v = acc[m][n][j] + bv;
        short h = f2bf(v);
        float res = v - bf2f(h);
        Chi[row * N + col] = h;
        Clo[row * N + col] = f2bf(res);
      }
  }
}

// ---------------------------------------------------------------------------
// Transpose V slices: Vb [g][1024 t][64 d] -> Vt [g][64 d][1024 t]
// ---------------------------------------------------------------------------
__global__ __launch_bounds__(256) void k_transpose_v(const short* __restrict__ Vb,
                                                     short* __restrict__ Vt) {
  __shared__ __align__(16) short T[64][264];
  int g = blockIdx.y, t0 = blockIdx.x * 256;
  int tid = threadIdx.x;
  const short* src = Vb + (long)g * 65536;
#pragma unroll
  for (int i = 0; i < 8; ++i) {
    int c = i * 256 + tid;
    int t = c >> 3, dc = (c & 7) * 8;
    bf16x8 v = *(const bf16x8*)(src + (long)(t0 + t) * 64 + dc);
#pragma unroll
    for (int e = 0; e < 8; ++e) T[dc + e][t] = v[e];
  }
  __syncthreads();
  short* dst = Vt + (long)g * 65536;
#pragma unroll
  for (int i = 0; i < 8; ++i) {
    int c = i * 256 + tid;
    int d = c >> 5, tc = (c & 31) * 8;
    bf16x8 v = *(const bf16x8*)(&T[d][tc]);
    *(bf16x8*)(dst + (long)d * 1024 + t0 + tc) = v;
  }
}

// ---------------------------------------------------------------------------
// k_mu: Thr[g,s] = (q_s . sum_t k_t) * NORM / 1024  (analytic row-mean of S)
// one block per slice g; deterministic (no atomics)
// ---------------------------------------------------------------------------
__global__ __launch_bounds__(256) void k_mu(
    const short* __restrict__ Khi, const short* __restrict__ Klo,
    const short* __restrict__ Qhi, const short* __restrict__ Qlo,
    float* __restrict__ Thr) {
  __shared__ float tmp[32][64];
  __shared__ float ksum[64];
  const int g = blockIdx.x, tid = threadIdx.x;
  const int d8 = tid & 7, tq = tid >> 3;
  const short* kh = Khi + (long)g * 65536;
  const short* kl = Klo + (long)g * 65536;
  float acc[8] = {};
  for (int t = tq; t < 1024; t += 32) {
    bf16x8 a = *(const bf16x8*)(kh + t * 64 + d8 * 8);
    bf16x8 b = *(const bf16x8*)(kl + t * 64 + d8 * 8);
#pragma unroll
    for (int e = 0; e < 8; ++e) acc[e] += bf2f(a[e]) + bf2f(b[e]);
  }
#pragma unroll
  for (int e = 0; e < 8; ++e) tmp[tq][d8 * 8 + e] = acc[e];
  __syncthreads();
  if (tid < 64) {
    float s = 0.f;
#pragma unroll
    for (int q = 0; q < 32; ++q) s += tmp[q][tid];
    ksum[tid] = s;
  }
  __syncthreads();
  const float c = 0.03125f / 1024.f;
  for (int s = tid; s < 1024; s += 256) {
    const short* qh = Qhi + (long)g * 65536 + s * 64;
    const short* ql = Qlo + (long)g * 65536 + s * 64;
    float dot = 0.f;
#pragma unroll
    for (int d0 = 0; d0 < 64; d0 += 8) {
      bf16x8 a = *(const bf16x8*)(qh + d0);
      bf16x8 b = *(const bf16x8*)(ql + d0);
#pragma unroll
      for (int e = 0; e < 8; ++e) dot += (bf2f(a[e]) + bf2f(b[e])) * ksum[d0 + e];
    }
    Thr[g * 1024 + s] = dot * c;
  }
}

// ---------------------------------------------------------------------------
// Pass A (transposed ownership): block owns 64 columns t, iterates Q tiles.
// rL[t] = 1 / sum_s exp(S[s,t]).  Register accumulation, no atomics.
// ---------------------------------------------------------------------------
__global__ __launch_bounds__(256, 4) void k_passA(
    const short* __restrict__ Qhi, const short* __restrict__ Qlo,
    const short* __restrict__ Khi, const short* __restrict__ Klo,
    float* __restrict__ rL) {
  __shared__ __align__(16) short KsH[64 * 64], KsL[64 * 64];
  __shared__ __align__(16) short QsH[64 * 64], QsL[64 * 64];
  const int g = blockIdx.y, tb = blockIdx.x;
  const int tid = threadIdx.x, lane = tid & 63;
  const int w = tid >> 6;
  const int lo = lane & 15, hi4 = lane >> 4;
  const long gbase = (long)g * 131072;  // bytes
  // stage block's K rows once
#pragma unroll
  for (int i = 0; i < 2; ++i) {
    int c = i * 256 + tid;
    int r = c >> 3;
    int wi = ((c & 7) * 16) ^ ((r & 7) << 4);
    glds16((const char*)Khi + gbase + (long)(tb * 64 + r) * 128 + wi, (char*)KsH + c * 16);
    glds16((const char*)Klo + gbase + (long)(tb * 64 + r) * 128 + wi, (char*)KsL + c * 16);
  }
  __syncthreads();
  bf16x8 kh[2], kl[2];
#pragma unroll
  for (int kk = 0; kk < 2; ++kk) {
    int r = w * 16 + lo;
    int off = r * 128 + ((kk * 64 + hi4 * 16) ^ ((r & 7) << 4));
    kh[kk] = *(const bf16x8*)((const char*)KsH + off);
    kl[kk] = *(const bf16x8*)((const char*)KsL + off);
  }
  float Lacc[4] = {};
  for (int sb = 0; sb < 16; ++sb) {
#pragma unroll
    for (int i = 0; i < 2; ++i) {
      int c = i * 256 + tid;
      int r = c >> 3;
      int wi = ((c & 7) * 16) ^ ((r & 7) << 4);
      glds16((const char*)Qhi + gbase + (long)(sb * 64 + r) * 128 + wi, (char*)QsH + c * 16);
      glds16((const char*)Qlo + gbase + (long)(sb * 64 + r) * 128 + wi, (char*)QsL + c * 16);
    }
    __syncthreads();
    f32x4 s[4] = {};
#pragma unroll
    for (int kk = 0; kk < 2; ++kk) {
#pragma unroll
      for (int n = 0; n < 4; ++n) {
        int r = n * 16 + lo;
        int off = r * 128 + ((kk * 64 + hi4 * 16) ^ ((r & 7) << 4));
        bf16x8 qfh = *(const bf16x8*)((const char*)QsH + off);
        bf16x8 qfl = *(const bf16x8*)((const char*)QsL + off);
        __builtin_amdgcn_s_setprio(1);
        s[n] = __builtin_amdgcn_mfma_f32_16x16x32_bf16(kh[kk], qfh, s[n], 0, 0, 0);
        s[n] = __builtin_amdgcn_mfma_f32_16x16x32_bf16(kh[kk], qfl, s[n], 0, 0, 0);
        s[n] = __builtin_amdgcn_mfma_f32_16x16x32_bf16(kl[kk], qfh, s[n], 0, 0, 0);
        __builtin_amdgcn_s_setprio(0);
      }
    }
#pragma unroll
    for (int n = 0; n < 4; ++n)
#pragma unroll
      for (int j = 0; j < 4; ++j)
        Lacc[j] += __expf(s[n][j] * 0.03125f);
    __syncthreads();
  }
#pragma unroll
  for (int j = 0; j < 4; ++j) {
    float v = Lacc[j];
    v += __shfl_xor(v, 1);
    v += __shfl_xor(v, 2);
    v += __shfl_xor(v, 4);
    v += __shfl_xor(v, 8);
    if (lo == 0) rL[g * 1024 + tb * 64 + w * 16 + hi4 * 4 + j] = 1.0f / v;
  }
}

// ---------------------------------------------------------------------------
// Pass B: recompute S (split), P1 = e*rL, P2 = mask*e, merged dual-PV,
// out_pre = 0.5*(O1/R + O2/Z), bf16.  Wave owns 16 rows x 64 cols.
// LDS = 40 KB -> 4 blocks/CU.
// ---------------------------------------------------------------------------
__global__ __launch_bounds__(256, 4) void k_passB(
    const short* __restrict__ Qhi, const short* __restrict__ Qlo,
    const short* __restrict__ Khi, const short* __restrict__ Klo,
    const short* __restrict__ Vt, const float* __restrict__ rL,
    const float* __restrict__ Thr, short* __restrict__ Pre,
    const int* __restrict__ rmask) {
  __shared__ __align__(16) short KsH[64 * 64], KsL[64 * 64];
  __shared__ __align__(16) short Vs[64 * 64];
  __shared__ __align__(16) short Ps1[64 * 64], Ps2[64 * 64];
  const int g = blockIdx.y, rb = blockIdx.x;
  const int tid = threadIdx.x, lane = tid & 63;
  const int w = tid >> 6;
  const int lo = lane & 15, hi4 = lane >> 4;
  const long gbase = (long)g * 131072;
  const bool use_mask = (*rmask != 0);
  // Q fragments direct from global (one-time): wave rows = rb*64 + w*16 + lo
  bf16x8 qfh[2], qfl[2];
  {
    const char* qrh = (const char*)Qhi + gbase + (long)(rb * 64 + w * 16 + lo) * 128;
    const char* qrl = (const char*)Qlo + gbase + (long)(rb * 64 + w * 16 + lo) * 128;
#pragma unroll
    for (int kk = 0; kk < 2; ++kk) {
      qfh[kk] = *(const bf16x8*)(qrh + kk * 64 + hi4 * 16);
      qfl[kk] = *(const bf16x8*)(qrl + kk * 64 + hi4 * 16);
    }
  }
  float thre[4];
#pragma unroll
  for (int j = 0; j < 4; ++j)
    thre[j] = Thr[g * 1024 + rb * 64 + w * 16 + hi4 * 4 + j];
  float rpart[4] = {}, zpart[4] = {};
  f32x4 o1[4] = {}, o2[4] = {};

  for (int tb = 0; tb < 16; ++tb) {
#pragma unroll
    for (int i = 0; i < 2; ++i) {
      int c = i * 256 + tid;
      int r = c >> 3;
      int wi = ((c & 7) * 16) ^ ((r & 7) << 4);
      glds16((const char*)Khi + gbase + (long)(tb * 64 + r) * 128 + wi, (char*)KsH + c * 16);
      glds16((const char*)Klo + gbase + (long)(tb * 64 + r) * 128 + wi, (char*)KsL + c * 16);
      glds16((const char*)Vt + gbase + (long)r * 2048 + tb * 128 + wi, (char*)Vs + c * 16);
    }
    __syncthreads();
    // --- QK^T (split, 24 MFMA/wave) ---
    f32x4 s[4] = {};
#pragma unroll
    for (int kk = 0; kk < 2; ++kk) {
#pragma unroll
      for (int n = 0; n < 4; ++n) {
        int r = n * 16 + lo;
        int off = r * 128 + ((kk * 64 + hi4 * 16) ^ ((r & 7) << 4));
        bf16x8 kh = *(const bf16x8*)((const char*)KsH + off);
        bf16x8 kl = *(const bf16x8*)((const char*)KsL + off);
        __builtin_amdgcn_s_setprio(1);
        s[n] = __builtin_amdgcn_mfma_f32_16x16x32_bf16(qfh[kk], kh, s[n], 0, 0, 0);
        s[n] = __builtin_amdgcn_mfma_f32_16x16x32_bf16(qfh[kk], kl, s[n], 0, 0, 0);
        s[n] = __builtin_amdgcn_mfma_f32_16x16x32_bf16(qfl[kk], kh, s[n], 0, 0, 0);
        __builtin_amdgcn_s_setprio(0);
      }
    }
    // --- softmax pieces + both P stores ---
    float rLv[4];
#pragma unroll
    for (int n = 0; n < 4; ++n) rLv[n] = rL[g * 1024 + tb * 64 + n * 16 + lo];
#pragma unroll
    for (int n = 0; n < 4; ++n)
#pragma unroll
      for (int j = 0; j < 4; ++j) {
        float sv = s[n][j] * 0.03125f;
        float e = __expf(sv);
        float p1 = e * rLv[n];
        rpart[j] += p1;
        float p2 = (!use_mask || (sv > thre[j])) ? e : 0.f;
        zpart[j] += p2;
        int row = w * 16 + hi4 * 4 + j;
        int colb = (n * 16 + lo) * 2;
        int boff = row * 128 + (colb ^ ((row & 7) << 4));
        *(short*)((char*)Ps1 + boff) = f2bf(p1);
        *(short*)((char*)Ps2 + boff) = f2bf(p2);
      }
    __syncthreads();
    // --- merged dual PV (16 MFMA/wave) ---
    {
      int prow = w * 16 + lo;
#pragma unroll
      for (int kk = 0; kk < 2; ++kk) {
        int poff = prow * 128 + ((kk * 64 + hi4 * 16) ^ ((prow & 7) << 4));
        bf16x8 pa1 = *(const bf16x8*)((const char*)Ps1 + poff);
        bf16x8 pa2 = *(const bf16x8*)((const char*)Ps2 + poff);
#pragma unroll
        for (int n = 0; n < 4; ++n) {
          int d = n * 16 + lo;
          bf16x8 vb = *(const bf16x8*)((const char*)Vs + d * 128 +
                                       ((kk * 64 + hi4 * 16) ^ ((d & 7) << 4)));
          __builtin_amdgcn_s_setprio(1);
          o1[n] = __builtin_amdgcn_mfma_f32_16x16x32_bf16(pa1, vb, o1[n], 0, 0, 0);
          o2[n] = __builtin_amdgcn_mfma_f32_16x16x32_bf16(pa2, vb, o2[n], 0, 0, 0);
          __builtin_amdgcn_s_setprio(0);
        }
      }
    }
    __syncthreads();
  }
  // --- final: in-register butterfly row reductions, write Pre ---
  float rfin[4], zfin[4];
#pragma unroll
  for (int j = 0; j < 4; ++j) {
    float r = rpart[j], z = zpart[j];
    r += __shfl_xor(r, 1); r += __shfl_xor(r, 2); r += __shfl_xor(r, 4); r += __shfl_xor(r, 8);
    z += __shfl_xor(z, 1); z += __shfl_xor(z, 2); z += __shfl_xor(z, 4); z += __shfl_xor(z, 8);
    rfin[j] = fmaxf(r, 1e-12f);
    zfin[j] = fmaxf(z, 1e-30f);
  }
#pragma unroll
  for (int n = 0; n < 4; ++n)
#pragma unroll
    for (int j = 0; j < 4; ++j) {
      int rl_ = w * 16 + hi4 * 4 + j;
      float val = 0.5f * (o1[n][j] / rfin[j] + o2[n][j] / zfin[j]);
      Pre[(long)g * 65536 + (long)(rb * 64 + rl_) * 64 + n * 16 + lo] = f2bf(val);
    }
}

// ---------------------------------------------------------------------------
extern "C" void kernel_launch(void* const* d_in, const int* in_sizes, int n_in,
                              void* d_out, int out_size, void* d_ws, size_t ws_size,
                              hipStream_t stream) {
  const float* x  = (const float*)d_in[0];
  const float* y  = (const float*)d_in[1];
  const float* Wq = (const float*)d_in[2];
  const float* bq = (const float*)d_in[3];
  const float* Wk = (const float*)d_in[4];
  const float* bk = (const float*)d_in[5];
  const float* Wv = (const float*)d_in[6];
  const float* bv = (const float*)d_in[7];
  const float* Wo = (const float*)d_in[8];
  const float* bo = (const float*)d_in[9];
  const int* rm   = (const int*)d_in[10];
  float* out = (float*)d_out;

  char* ws = (char*)d_ws;
  size_t off = 0;
  auto alloc = [&](size_t bytes) {
    char* p = ws + off;
    off += (bytes + 255) & ~(size_t)255;
    return p;
  };
  short* xhi  = (short*)alloc(4194304 * 2);
  short* xlo  = (short*)alloc(4194304 * 2);
  short* yhi  = (short*)alloc(4194304 * 2);
  short* ylo  = (short*)alloc(4194304 * 2);
  short* wqhi = (short*)alloc(1048576 * 2);
  short* wqlo = (short*)alloc(1048576 * 2);
  short* wkhi = (short*)alloc(1048576 * 2);
  short* wklo = (short*)alloc(1048576 * 2);
  short* wvhi = (short*)alloc(1048576 * 2);
  short* wohi = (short*)alloc(1048576 * 2);
  short* QhiB = (short*)alloc(4194304 * 2);
  short* QloB = (short*)alloc(4194304 * 2);
  short* KhiB = (short*)alloc(4194304 * 2);
  short* KloB = (short*)alloc(4194304 * 2);
  short* Vb   = (short*)alloc(4194304 * 2);
  short* VtB  = (short*)alloc(4194304 * 2);
  short* pre  = (short*)alloc(4194304 * 2);
  float* rLbuf = (float*)alloc(65536 * 4);
  float* Thr   = (float*)alloc(65536 * 4);
  if (off > ws_size) return;

  k_convert<<<dim3(4096, 6), 256, 0, stream>>>(x, y, Wq, Wk, Wv, Wo, xhi, xlo, yhi, ylo,
                                               wqhi, wqlo, wkhi, wklo, wvhi, wohi);

  k_gemm_split<<<dim3(16, 32), 256, 0, stream>>>(xhi, xlo, wqhi, wqlo, bq, QhiB, QloB,
                                                 4096, 1024, 1024);
  k_gemm_split<<<dim3(16, 32), 256, 0, stream>>>(yhi, ylo, wkhi, wklo, bk, KhiB, KloB,
                                                 4096, 1024, 1024);
  k_gemm_plain<0><<<dim3(8, 32), 256, 0, stream>>>(yhi, wvhi, bv, Vb, 4096, 1024, 1024);
  k_transpose_v<<<dim3(4, 64), 256, 0, stream>>>(Vb, VtB);
  k_mu<<<64, 256, 0, stream>>>(KhiB, KloB, QhiB, QloB, Thr);
  k_passA<<<dim3(16, 64), 256, 0, stream>>>(QhiB, QloB, KhiB, KloB, rLbuf);
  k_passB<<<dim3(16, 64), 256, 0, stream>>>(QhiB, QloB, KhiB, KloB, VtB, rLbuf, Thr, pre, rm);
  k_gemm_plain<1><<<dim3(8, 32), 256, 0, stream>>>(pre, wohi, bo, out, 4096, 1024, 1024);
}

// Round 5
// 229.303 us; speedup vs baseline: 1.1927x; 1.1114x over previous
//
#include <hip/hip_runtime.h>
#include <hip/hip_bf16.h>
#include <stdint.h>

typedef float f32x4 __attribute__((ext_vector_type(4)));
typedef short bf16x8 __attribute__((ext_vector_type(8)));

#define DEV static __device__ __forceinline__

DEV float bf2f(short u) {
  union { float f; unsigned i; } v;
  v.i = ((unsigned)(unsigned short)u) << 16;
  return v.f;
}
DEV short f2bf(float f) {
  union { float f; unsigned i; } v;
  v.f = f;
  unsigned lsb = (v.i >> 16) & 1u;
  v.i += 0x7fffu + lsb;
  return (short)(v.i >> 16);
}
DEV float lo16f(unsigned u) {
  union { float f; unsigned i; } v;
  v.i = u << 16;
  return v.f;
}
DEV float hi16f(unsigned u) {
  union { float f; unsigned i; } v;
  v.i = u & 0xffff0000u;
  return v.f;
}
DEV unsigned pk2bf(float a, float b) {
  return (unsigned)(unsigned short)f2bf(a) | ((unsigned)(unsigned short)f2bf(b) << 16);
}

DEV void glds16(const void* g, void* l) {
  __builtin_amdgcn_global_load_lds(
      (const __attribute__((address_space(1))) void*)g,
      (__attribute__((address_space(3))) void*)l, 16, 0, 0);
}

// ---------------------------------------------------------------------------
// Convert fp32 -> bf16 hi/lo splits (x, y, Wq, Wk) and bf16 (Wv, Wo)
// ---------------------------------------------------------------------------
__global__ __launch_bounds__(256) void k_convert(
    const float* __restrict__ x, const float* __restrict__ y,
    const float* __restrict__ wq, const float* __restrict__ wk,
    const float* __restrict__ wv, const float* __restrict__ wo,
    short* __restrict__ xhi, short* __restrict__ xlo,
    short* __restrict__ yhi, short* __restrict__ ylo,
    short* __restrict__ wqhi, short* __restrict__ wqlo,
    short* __restrict__ wkhi, short* __restrict__ wklo,
    short* __restrict__ wvhi, short* __restrict__ wohi) {
  const float* src; short* hi; short* lo; int n;
  switch (blockIdx.y) {
    case 0: src = x;  hi = xhi;  lo = xlo;    n = 4194304; break;
    case 1: src = y;  hi = yhi;  lo = ylo;    n = 4194304; break;
    case 2: src = wq; hi = wqhi; lo = wqlo;   n = 1048576; break;
    case 3: src = wk; hi = wkhi; lo = wklo;   n = 1048576; break;
    case 4: src = wv; hi = wvhi; lo = nullptr; n = 1048576; break;
    default: src = wo; hi = wohi; lo = nullptr; n = 1048576; break;
  }
  int i4 = blockIdx.x * 256 + threadIdx.x;
  if (i4 * 4 >= n) return;
  float4 v = ((const float4*)src)[i4];
  short4 h, l;
  float* pv = (float*)&v;
  short* ph = (short*)&h;
  short* pl = (short*)&l;
#pragma unroll
  for (int e = 0; e < 4; ++e) {
    short hh = f2bf(pv[e]);
    ph[e] = hh;
    pl[e] = f2bf(pv[e] - bf2f(hh));
  }
  ((short4*)hi)[i4] = h;
  if (lo) ((short4*)lo)[i4] = l;
}

// ---------------------------------------------------------------------------
// XCD-pinned block remap for M=4096(32 row-panels) x N=1024(8 col-blocks):
// all 8 col-blocks of a row-panel land on the same XCD (wg%8 == row%8).
// ---------------------------------------------------------------------------
DEV void gemm_block_map(int wg, long& bRow, long& bCol) {
  int rlow = wg & 7, c = (wg >> 3) & 7, rhigh = wg >> 6;
  bRow = (long)(rhigh * 8 + rlow) * 128;
  bCol = (long)c * 128;
}

// ---------------------------------------------------------------------------
// Plain bf16 NT GEMM with bias: 128x128 tile, BK=64, 8 waves (512 thr).
// OUT_F32=1: fp32 row-major C.  OUT_F32=0: bf16 row-major C.
// ---------------------------------------------------------------------------
template <int OUT_F32>
__global__ __launch_bounds__(512) void k_gemm_plain(
    const short* __restrict__ A, const short* __restrict__ B,
    const float* __restrict__ bias, void* __restrict__ C, int M, int N, int K) {
  __shared__ __align__(16) short As[128 * 64];
  __shared__ __align__(16) short Bs[128 * 64];
  const int tid = threadIdx.x, lane = tid & 63;
  const int w = tid >> 6, wr = w >> 1, wc = w & 1;
  const int lo = lane & 15, hi4 = lane >> 4;
  long bRow, bCol;
  gemm_block_map(blockIdx.x, bRow, bCol);
  f32x4 acc[2][4] = {};
  const int nks = K >> 6;
  for (int ks = 0; ks < nks; ++ks) {
#pragma unroll
    for (int i = 0; i < 2; ++i) {
      int c = i * 512 + tid;
      int r = c >> 3;
      int wi = ((c & 7) * 16) ^ ((r & 7) << 4);
      glds16((const char*)A + (bRow + r) * (long)(K * 2) + ks * 128 + wi, (char*)As + c * 16);
      glds16((const char*)B + (bCol + r) * (long)(K * 2) + ks * 128 + wi, (char*)Bs + c * 16);
    }
    __syncthreads();
#pragma unroll
    for (int kk = 0; kk < 2; ++kk) {
      bf16x8 af[2], bfr[4];
#pragma unroll
      for (int m = 0; m < 2; ++m) {
        int r = wr * 32 + m * 16 + lo;
        af[m] = *(const bf16x8*)((const char*)As + r * 128 + ((kk * 64 + hi4 * 16) ^ ((r & 7) << 4)));
      }
#pragma unroll
      for (int n = 0; n < 4; ++n) {
        int r = wc * 64 + n * 16 + lo;
        bfr[n] = *(const bf16x8*)((const char*)Bs + r * 128 + ((kk * 64 + hi4 * 16) ^ ((r & 7) << 4)));
      }
#pragma unroll
      for (int m = 0; m < 2; ++m)
#pragma unroll
        for (int n = 0; n < 4; ++n)
          acc[m][n] = __builtin_amdgcn_mfma_f32_16x16x32_bf16(af[m], bfr[n], acc[m][n], 0, 0, 0);
    }
    __syncthreads();
  }
#pragma unroll
  for (int n = 0; n < 4; ++n) {
    long col = bCol + wc * 64 + n * 16 + lo;
    float bv = bias[col];
#pragma unroll
    for (int m = 0; m < 2; ++m) {
      long row0 = bRow + wr * 32 + m * 16 + hi4 * 4;
#pragma unroll
      for (int j = 0; j < 4; ++j) {
        float v = acc[m][n][j] + bv;
        if (OUT_F32) ((float*)C)[(row0 + j) * N + col] = v;
        else ((short*)C)[(row0 + j) * N + col] = f2bf(v);
      }
    }
  }
}

// ---------------------------------------------------------------------------
// Split-precision NT GEMM: C = (Ahi+Alo)(Bhi+Blo)^T + bias  (3-term MFMA)
// 128x128 tile, BK=64, 8 waves (512 thr), outputs hi/lo bf16.
// ---------------------------------------------------------------------------
__global__ __launch_bounds__(512) void k_gemm_split(
    const short* __restrict__ Ahi, const short* __restrict__ Alo,
    const short* __restrict__ Bhi, const short* __restrict__ Blo,
    const float* __restrict__ bias, short* __restrict__ Chi,
    short* __restrict__ Clo, int M, int N, int K) {
  __shared__ __align__(16) short AsH[128 * 64], AsL[128 * 64];
  __shared__ __align__(16) short BsH[128 * 64], BsL[128 * 64];
  const int tid = threadIdx.x, lane = tid & 63;
  const int w = tid >> 6, wr = w >> 1, wc = w & 1;
  const int lo = lane & 15, hi4 = lane >> 4;
  long bRow, bCol;
  gemm_block_map(blockIdx.x, bRow, bCol);
  f32x4 acc[2][4] = {};
  const int nks = K >> 6;
  for (int ks = 0; ks < nks; ++ks) {
#pragma unroll
    for (int i = 0; i < 2; ++i) {
      int c = i * 512 + tid;
      int r = c >> 3;
      int wi = ((c & 7) * 16) ^ ((r & 7) << 4);
      glds16((const char*)Ahi + (bRow + r) * (long)(K * 2) + ks * 128 + wi, (char*)AsH + c * 16);
      glds16((const char*)Alo + (bRow + r) * (long)(K * 2) + ks * 128 + wi, (char*)AsL + c * 16);
      glds16((const char*)Bhi + (bCol + r) * (long)(K * 2) + ks * 128 + wi, (char*)BsH + c * 16);
      glds16((const char*)Blo + (bCol + r) * (long)(K * 2) + ks * 128 + wi, (char*)BsL + c * 16);
    }
    __syncthreads();
#pragma unroll
    for (int kk = 0; kk < 2; ++kk) {
      bf16x8 ah[2], al[2], bh[4], bl[4];
#pragma unroll
      for (int m = 0; m < 2; ++m) {
        int r = wr * 32 + m * 16 + lo;
        int off = r * 128 + ((kk * 64 + hi4 * 16) ^ ((r & 7) << 4));
        ah[m] = *(const bf16x8*)((const char*)AsH + off);
        al[m] = *(const bf16x8*)((const char*)AsL + off);
      }
#pragma unroll
      for (int n = 0; n < 4; ++n) {
        int r = wc * 64 + n * 16 + lo;
        int off = r * 128 + ((kk * 64 + hi4 * 16) ^ ((r & 7) << 4));
        bh[n] = *(const bf16x8*)((const char*)BsH + off);
        bl[n] = *(const bf16x8*)((const char*)BsL + off);
      }
#pragma unroll
      for (int m = 0; m < 2; ++m)
#pragma unroll
        for (int n = 0; n < 4; ++n) {
          acc[m][n] = __builtin_amdgcn_mfma_f32_16x16x32_bf16(ah[m], bh[n], acc[m][n], 0, 0, 0);
          acc[m][n] = __builtin_amdgcn_mfma_f32_16x16x32_bf16(ah[m], bl[n], acc[m][n], 0, 0, 0);
          acc[m][n] = __builtin_amdgcn_mfma_f32_16x16x32_bf16(al[m], bh[n], acc[m][n], 0, 0, 0);
        }
    }
    __syncthreads();
  }
#pragma unroll
  for (int n = 0; n < 4; ++n) {
    long col = bCol + wc * 64 + n * 16 + lo;
    float bv = bias[col];
#pragma unroll
    for (int m = 0; m < 2; ++m)
#pragma unroll
      for (int j = 0; j < 4; ++j) {
        long row = bRow + wr * 32 + m * 16 + hi4 * 4 + j;
        float v = acc[m][n][j] + bv;
        short h = f2bf(v);
        float res = v - bf2f(h);
        Chi[row * N + col] = h;
        Clo[row * N + col] = f2bf(res);
      }
  }
}

// ---------------------------------------------------------------------------
// Transpose V slices (flat-index transform, PROVEN r1/r2):
// Vb flat [g][1024 t][64 d] -> Vt [g][64 d][1024 t]
// ---------------------------------------------------------------------------
__global__ __launch_bounds__(256) void k_transpose_v(const short* __restrict__ Vb,
                                                     short* __restrict__ Vt) {
  __shared__ __align__(16) short T[64][264];
  int g = blockIdx.y, t0 = blockIdx.x * 256;
  int tid = threadIdx.x;
  const short* src = Vb + (long)g * 65536;
#pragma unroll
  for (int i = 0; i < 8; ++i) {
    int c = i * 256 + tid;  // 0..2047
    int t = c >> 3, dc = (c & 7) * 8;
    bf16x8 v = *(const bf16x8*)(src + (long)(t0 + t) * 64 + dc);
#pragma unroll
    for (int e = 0; e < 8; ++e) T[dc + e][t] = v[e];
  }
  __syncthreads();
  short* dst = Vt + (long)g * 65536;
#pragma unroll
  for (int i = 0; i < 8; ++i) {
    int c = i * 256 + tid;
    int d = c >> 5, tc = (c & 31) * 8;
    bf16x8 v = *(const bf16x8*)(&T[d][tc]);
    *(bf16x8*)(dst + (long)d * 1024 + t0 + tc) = v;
  }
}

// ---------------------------------------------------------------------------
// k_mu: Thr[g,s] = (q_s . sum_t k_t) * NORM / 1024  (analytic row-mean of S)
// ---------------------------------------------------------------------------
__global__ __launch_bounds__(256) void k_mu(
    const short* __restrict__ Khi, const short* __restrict__ Klo,
    const short* __restrict__ Qhi, const short* __restrict__ Qlo,
    float* __restrict__ Thr) {
  __shared__ float tmp[32][64];
  __shared__ float ksum[64];
  const int g = blockIdx.x, tid = threadIdx.x;
  const int d8 = tid & 7, tq = tid >> 3;
  const short* kh = Khi + (long)g * 65536;
  const short* kl = Klo + (long)g * 65536;
  float acc[8] = {};
  for (int t = tq; t < 1024; t += 32) {
    bf16x8 a = *(const bf16x8*)(kh + t * 64 + d8 * 8);
    bf16x8 b = *(const bf16x8*)(kl + t * 64 + d8 * 8);
#pragma unroll
    for (int e = 0; e < 8; ++e) acc[e] += bf2f(a[e]) + bf2f(b[e]);
  }
#pragma unroll
  for (int e = 0; e < 8; ++e) tmp[tq][d8 * 8 + e] = acc[e];
  __syncthreads();
  if (tid < 64) {
    float s = 0.f;
#pragma unroll
    for (int q = 0; q < 32; ++q) s += tmp[q][tid];
    ksum[tid] = s;
  }
  __syncthreads();
  const float c = 0.03125f / 1024.f;
  for (int s = tid; s < 1024; s += 256) {
    const short* qh = Qhi + (long)g * 65536 + s * 64;
    const short* ql = Qlo + (long)g * 65536 + s * 64;
    float dot = 0.f;
#pragma unroll
    for (int d0 = 0; d0 < 64; d0 += 8) {
      bf16x8 a = *(const bf16x8*)(qh + d0);
      bf16x8 b = *(const bf16x8*)(ql + d0);
#pragma unroll
      for (int e = 0; e < 8; ++e) dot += (bf2f(a[e]) + bf2f(b[e])) * ksum[d0 + e];
    }
    Thr[g * 1024 + s] = dot * c;
  }
}

// ---------------------------------------------------------------------------
// Pass A (plain bf16): block owns 64 columns t of one slice; iterates Q tiles.
// rL[t] = 1 / sum_s exp(S_plain[s,t]).
// ---------------------------------------------------------------------------
__global__ __launch_bounds__(256) void k_passA(
    const short* __restrict__ Qhi, const short* __restrict__ Khi,
    float* __restrict__ rL) {
  __shared__ __align__(16) short KsH[64 * 64];
  __shared__ __align__(16) short QsH[64 * 64];
  const int wg = blockIdx.x;
  const int g = (wg & 7) | ((wg >> 7) << 3);  // slice pinned to XCD g&7
  const int tb = (wg >> 3) & 15;
  const int tid = threadIdx.x, lane = tid & 63;
  const int w = tid >> 6;
  const int lo = lane & 15, hi4 = lane >> 4;
  const long gbase = (long)g * 131072;  // bytes
#pragma unroll
  for (int i = 0; i < 2; ++i) {
    int c = i * 256 + tid;
    int r = c >> 3;
    int wi = ((c & 7) * 16) ^ ((r & 7) << 4);
    glds16((const char*)Khi + gbase + (long)(tb * 64 + r) * 128 + wi, (char*)KsH + c * 16);
  }
  __syncthreads();
  bf16x8 kh[2];
#pragma unroll
  for (int kk = 0; kk < 2; ++kk) {
    int r = w * 16 + lo;
    kh[kk] = *(const bf16x8*)((const char*)KsH + r * 128 + ((kk * 64 + hi4 * 16) ^ ((r & 7) << 4)));
  }
  float Lacc[4] = {};
  for (int sb = 0; sb < 16; ++sb) {
#pragma unroll
    for (int i = 0; i < 2; ++i) {
      int c = i * 256 + tid;
      int r = c >> 3;
      int wi = ((c & 7) * 16) ^ ((r & 7) << 4);
      glds16((const char*)Qhi + gbase + (long)(sb * 64 + r) * 128 + wi, (char*)QsH + c * 16);
    }
    __syncthreads();
    f32x4 s[4] = {};
#pragma unroll
    for (int kk = 0; kk < 2; ++kk) {
#pragma unroll
      for (int n = 0; n < 4; ++n) {
        int r = n * 16 + lo;
        bf16x8 qf = *(const bf16x8*)((const char*)QsH + r * 128 +
                                     ((kk * 64 + hi4 * 16) ^ ((r & 7) << 4)));
        __builtin_amdgcn_s_setprio(1);
        s[n] = __builtin_amdgcn_mfma_f32_16x16x32_bf16(kh[kk], qf, s[n], 0, 0, 0);
        __builtin_amdgcn_s_setprio(0);
      }
    }
#pragma unroll
    for (int n = 0; n < 4; ++n)
#pragma unroll
      for (int j = 0; j < 4; ++j)
        Lacc[j] += __expf(s[n][j] * 0.03125f);
    __syncthreads();
  }
#pragma unroll
  for (int j = 0; j < 4; ++j) {
    float v = Lacc[j];
    v += __shfl_xor(v, 1);
    v += __shfl_xor(v, 2);
    v += __shfl_xor(v, 4);
    v += __shfl_xor(v, 8);
    if (lo == 0) rL[g * 1024 + tb * 64 + w * 16 + hi4 * 4 + j] = 1.0f / v;
  }
}

// ---------------------------------------------------------------------------
// Pass B: S^T via swapped-operand split MFMA (lane owns s = w*16+lo, 4
// consecutive t per subtile) -> b64 P-stores, scalar thre/rpart/zpart.
// R/Z accumulate from ROUNDED values so the O/R ratio cancels rounding.
// Merged dual PV.
// ---------------------------------------------------------------------------
__global__ __launch_bounds__(256, 4) void k_passB(
    const short* __restrict__ Qhi, const short* __restrict__ Qlo,
    const short* __restrict__ Khi, const short* __restrict__ Klo,
    const short* __restrict__ Vt, const float* __restrict__ rL,
    const float* __restrict__ Thr, short* __restrict__ Pre,
    const int* __restrict__ rmask) {
  __shared__ __align__(16) short KsH[64 * 64], KsL[64 * 64];
  __shared__ __align__(16) short Vs[64 * 64];
  __shared__ __align__(16) short Ps1[64 * 64], Ps2[64 * 64];
  const int wg = blockIdx.x;
  const int g = (wg & 7) | ((wg >> 7) << 3);
  const int rb = (wg >> 3) & 15;
  const int tid = threadIdx.x, lane = tid & 63;
  const int w = tid >> 6;
  const int lo = lane & 15, hi4 = lane >> 4;
  const long gbase = (long)g * 131072;
  const bool use_mask = (*rmask != 0);
  const int srow = w * 16 + lo;  // this thread's block-local s row
  bf16x8 qfh[2], qfl[2];
  {
    const char* qrh = (const char*)Qhi + gbase + (long)(rb * 64 + srow) * 128;
    const char* qrl = (const char*)Qlo + gbase + (long)(rb * 64 + srow) * 128;
#pragma unroll
    for (int kk = 0; kk < 2; ++kk) {
      qfh[kk] = *(const bf16x8*)(qrh + kk * 64 + hi4 * 16);
      qfl[kk] = *(const bf16x8*)(qrl + kk * 64 + hi4 * 16);
    }
  }
  const float thre = Thr[g * 1024 + rb * 64 + srow];
  float rpart = 0.f, zpart = 0.f;
  f32x4 o1[4] = {}, o2[4] = {};

  for (int tb = 0; tb < 16; ++tb) {
#pragma unroll
    for (int i = 0; i < 2; ++i) {
      int c = i * 256 + tid;
      int r = c >> 3;
      int wi = ((c & 7) * 16) ^ ((r & 7) << 4);
      glds16((const char*)Khi + gbase + (long)(tb * 64 + r) * 128 + wi, (char*)KsH + c * 16);
      glds16((const char*)Klo + gbase + (long)(tb * 64 + r) * 128 + wi, (char*)KsL + c * 16);
      glds16((const char*)Vt + gbase + (long)r * 2048 + tb * 128 + wi, (char*)Vs + c * 16);
    }
    __syncthreads();
    // --- S^T = K.Q^T (split, 24 MFMA/wave): lane -> t = n*16+hi4*4+j, s = srow
    f32x4 s[4] = {};
#pragma unroll
    for (int kk = 0; kk < 2; ++kk) {
#pragma unroll
      for (int n = 0; n < 4; ++n) {
        int r = n * 16 + lo;
        int off = r * 128 + ((kk * 64 + hi4 * 16) ^ ((r & 7) << 4));
        bf16x8 kh = *(const bf16x8*)((const char*)KsH + off);
        bf16x8 kl = *(const bf16x8*)((const char*)KsL + off);
        __builtin_amdgcn_s_setprio(1);
        s[n] = __builtin_amdgcn_mfma_f32_16x16x32_bf16(kh, qfh[kk], s[n], 0, 0, 0);
        s[n] = __builtin_amdgcn_mfma_f32_16x16x32_bf16(kh, qfl[kk], s[n], 0, 0, 0);
        s[n] = __builtin_amdgcn_mfma_f32_16x16x32_bf16(kl, qfh[kk], s[n], 0, 0, 0);
        __builtin_amdgcn_s_setprio(0);
      }
    }
    // --- softmax pieces + vectorized dual P-store (software RNE pack) ---
#pragma unroll
    for (int n = 0; n < 4; ++n) {
      const float4 rl4 = *(const float4*)(rL + g * 1024 + tb * 64 + n * 16 + hi4 * 4);
      const float* rlp = (const float*)&rl4;
      float p1v[4], p2v[4];
#pragma unroll
      for (int j = 0; j < 4; ++j) {
        float sv = s[n][j] * 0.03125f;
        float e = __expf(sv);
        p1v[j] = e * rlp[j];
        p2v[j] = (!use_mask || (sv > thre)) ? e : 0.f;
      }
      unsigned u10 = pk2bf(p1v[0], p1v[1]);
      unsigned u11 = pk2bf(p1v[2], p1v[3]);
      unsigned u20 = pk2bf(p2v[0], p2v[1]);
      unsigned u21 = pk2bf(p2v[2], p2v[3]);
      rpart += (lo16f(u10) + hi16f(u10)) + (lo16f(u11) + hi16f(u11));
      zpart += (lo16f(u20) + hi16f(u20)) + (lo16f(u21) + hi16f(u21));
      int colb = n * 32 + hi4 * 8;
      int boff = srow * 128 + (colb ^ ((srow & 7) << 4));
      uint2 w1; w1.x = u10; w1.y = u11;
      uint2 w2; w2.x = u20; w2.y = u21;
      *(uint2*)((char*)Ps1 + boff) = w1;
      *(uint2*)((char*)Ps2 + boff) = w2;
    }
    __syncthreads();
    // --- merged dual PV (16 MFMA/wave) ---
#pragma unroll
    for (int kk = 0; kk < 2; ++kk) {
      int poff = srow * 128 + ((kk * 64 + hi4 * 16) ^ ((srow & 7) << 4));
      bf16x8 pa1 = *(const bf16x8*)((const char*)Ps1 + poff);
      bf16x8 pa2 = *(const bf16x8*)((const char*)Ps2 + poff);
#pragma unroll
      for (int n = 0; n < 4; ++n) {
        int d = n * 16 + lo;
        bf16x8 vb = *(const bf16x8*)((const char*)Vs + d * 128 +
                                     ((kk * 64 + hi4 * 16) ^ ((d & 7) << 4)));
        __builtin_amdgcn_s_setprio(1);
        o1[n] = __builtin_amdgcn_mfma_f32_16x16x32_bf16(pa1, vb, o1[n], 0, 0, 0);
        o2[n] = __builtin_amdgcn_mfma_f32_16x16x32_bf16(pa2, vb, o2[n], 0, 0, 0);
        __builtin_amdgcn_s_setprio(0);
      }
    }
    __syncthreads();
  }
  // --- row sums: reduce over the 4 hi4 t-quarters, redistribute via LDS ---
  float r = rpart;
  r += __shfl_xor(r, 16);
  r += __shfl_xor(r, 32);
  float z = zpart;
  z += __shfl_xor(z, 16);
  z += __shfl_xor(z, 32);
  float* Rbuf = (float*)Ps1;
  float* Zbuf = (float*)Ps2;
  if (hi4 == 0) { Rbuf[srow] = r; Zbuf[srow] = z; }
  __syncthreads();
#pragma unroll
  for (int n = 0; n < 4; ++n)
#pragma unroll
    for (int j = 0; j < 4; ++j) {
      int rl_ = w * 16 + hi4 * 4 + j;
      float rr = fmaxf(Rbuf[rl_], 1e-12f);
      float zz = fmaxf(Zbuf[rl_], 1e-30f);
      float val = 0.5f * (o1[n][j] / rr + o2[n][j] / zz);
      Pre[(long)g * 65536 + (long)(rb * 64 + rl_) * 64 + n * 16 + lo] = f2bf(val);
    }
}

// ---------------------------------------------------------------------------
extern "C" void kernel_launch(void* const* d_in, const int* in_sizes, int n_in,
                              void* d_out, int out_size, void* d_ws, size_t ws_size,
                              hipStream_t stream) {
  const float* x  = (const float*)d_in[0];
  const float* y  = (const float*)d_in[1];
  const float* Wq = (const float*)d_in[2];
  const float* bq = (const float*)d_in[3];
  const float* Wk = (const float*)d_in[4];
  const float* bk = (const float*)d_in[5];
  const float* Wv = (const float*)d_in[6];
  const float* bv = (const float*)d_in[7];
  const float* Wo = (const float*)d_in[8];
  const float* bo = (const float*)d_in[9];
  const int* rm   = (const int*)d_in[10];
  float* out = (float*)d_out;

  char* ws = (char*)d_ws;
  size_t off = 0;
  auto alloc = [&](size_t bytes) {
    char* p = ws + off;
    off += (bytes + 255) & ~(size_t)255;
    return p;
  };
  short* xhi  = (short*)alloc(4194304 * 2);
  short* xlo  = (short*)alloc(4194304 * 2);
  short* yhi  = (short*)alloc(4194304 * 2);
  short* ylo  = (short*)alloc(4194304 * 2);
  short* wqhi = (short*)alloc(1048576 * 2);
  short* wqlo = (short*)alloc(1048576 * 2);
  short* wkhi = (short*)alloc(1048576 * 2);
  short* wklo = (short*)alloc(1048576 * 2);
  short* wvhi = (short*)alloc(1048576 * 2);
  short* wohi = (short*)alloc(1048576 * 2);
  short* QhiB = (short*)alloc(4194304 * 2);
  short* QloB = (short*)alloc(4194304 * 2);
  short* KhiB = (short*)alloc(4194304 * 2);
  short* KloB = (short*)alloc(4194304 * 2);
  short* Vb   = (short*)alloc(4194304 * 2);
  short* VtB  = (short*)alloc(4194304 * 2);
  short* pre  = (short*)alloc(4194304 * 2);
  float* rLbuf = (float*)alloc(65536 * 4);
  float* Thr   = (float*)alloc(65536 * 4);
  if (off > ws_size) return;

  k_convert<<<dim3(4096, 6), 256, 0, stream>>>(x, y, Wq, Wk, Wv, Wo, xhi, xlo, yhi, ylo,
                                               wqhi, wqlo, wkhi, wklo, wvhi, wohi);

  k_gemm_split<<<256, 512, 0, stream>>>(xhi, xlo, wqhi, wqlo, bq, QhiB, QloB,
                                        4096, 1024, 1024);
  k_gemm_split<<<256, 512, 0, stream>>>(yhi, ylo, wkhi, wklo, bk, KhiB, KloB,
                                        4096, 1024, 1024);
  k_gemm_plain<0><<<256, 512, 0, stream>>>(yhi, wvhi, bv, Vb, 4096, 1024, 1024);
  k_transpose_v<<<dim3(4, 64), 256, 0, stream>>>(Vb, VtB);
  k_mu<<<64, 256, 0, stream>>>(KhiB, KloB, QhiB, QloB, Thr);
  k_passA<<<1024, 256, 0, stream>>>(QhiB, KhiB, rLbuf);
  k_passB<<<1024, 256, 0, stream>>>(QhiB, QloB, KhiB, KloB, VtB, rLbuf, Thr, pre, rm);
  k_gemm_plain<1><<<256, 512, 0, stream>>>(pre, wohi, bo, out, 4096, 1024, 1024);
}

// Round 7
// 220.766 us; speedup vs baseline: 1.2389x; 1.0387x over previous
//
#include <hip/hip_runtime.h>
#include <hip/hip_bf16.h>
#include <stdint.h>

typedef float f32x4 __attribute__((ext_vector_type(4)));
typedef short bf16x8 __attribute__((ext_vector_type(8)));

#define DEV static __device__ __forceinline__

DEV float bf2f(short u) {
  union { float f; unsigned i; } v;
  v.i = ((unsigned)(unsigned short)u) << 16;
  return v.f;
}
DEV short f2bf(float f) {
  union { float f; unsigned i; } v;
  v.f = f;
  unsigned lsb = (v.i >> 16) & 1u;
  v.i += 0x7fffu + lsb;
  return (short)(v.i >> 16);
}

DEV void glds16(const void* g, void* l) {
  __builtin_amdgcn_global_load_lds(
      (const __attribute__((address_space(1))) void*)g,
      (__attribute__((address_space(3))) void*)l, 16, 0, 0);
}

// ---------------------------------------------------------------------------
// Convert fp32 -> bf16 hi/lo splits (x, y, Wq, Wk) and bf16 (Wv, Wo)
// ---------------------------------------------------------------------------
__global__ __launch_bounds__(256) void k_convert(
    const float* __restrict__ x, const float* __restrict__ y,
    const float* __restrict__ wq, const float* __restrict__ wk,
    const float* __restrict__ wv, const float* __restrict__ wo,
    short* __restrict__ xhi, short* __restrict__ xlo,
    short* __restrict__ yhi, short* __restrict__ ylo,
    short* __restrict__ wqhi, short* __restrict__ wqlo,
    short* __restrict__ wkhi, short* __restrict__ wklo,
    short* __restrict__ wvhi, short* __restrict__ wohi) {
  const float* src; short* hi; short* lo; int n;
  switch (blockIdx.y) {
    case 0: src = x;  hi = xhi;  lo = xlo;    n = 4194304; break;
    case 1: src = y;  hi = yhi;  lo = ylo;    n = 4194304; break;
    case 2: src = wq; hi = wqhi; lo = wqlo;   n = 1048576; break;
    case 3: src = wk; hi = wkhi; lo = wklo;   n = 1048576; break;
    case 4: src = wv; hi = wvhi; lo = nullptr; n = 1048576; break;
    default: src = wo; hi = wohi; lo = nullptr; n = 1048576; break;
  }
  int i4 = blockIdx.x * 256 + threadIdx.x;
  if (i4 * 4 >= n) return;
  float4 v = ((const float4*)src)[i4];
  short4 h, l;
  float* pv = (float*)&v;
  short* ph = (short*)&h;
  short* pl = (short*)&l;
#pragma unroll
  for (int e = 0; e < 4; ++e) {
    short hh = f2bf(pv[e]);
    ph[e] = hh;
    pl[e] = f2bf(pv[e] - bf2f(hh));
  }
  ((short4*)hi)[i4] = h;
  if (lo) ((short4*)lo)[i4] = l;
}

// ---------------------------------------------------------------------------
// XCD-pinned block remap for M=4096(32 row-panels) x N=1024(8 col-blocks):
// all 8 col-blocks of a row-panel land on the same XCD (wg%8 == row%8).
// ---------------------------------------------------------------------------
DEV void gemm_block_map(int wg, long& bRow, long& bCol) {
  int rlow = wg & 7, c = (wg >> 3) & 7, rhigh = wg >> 6;
  bRow = (long)(rhigh * 8 + rlow) * 128;
  bCol = (long)c * 128;
}

// ---------------------------------------------------------------------------
// Plain bf16 NT GEMM with bias: 128x128 tile, BK=64, 8 waves (512 thr).
// OUT_F32=1: fp32 row-major C.  OUT_F32=0: bf16 row-major C.
// ---------------------------------------------------------------------------
template <int OUT_F32>
__global__ __launch_bounds__(512) void k_gemm_plain(
    const short* __restrict__ A, const short* __restrict__ B,
    const float* __restrict__ bias, void* __restrict__ C, int M, int N, int K) {
  __shared__ __align__(16) short As[128 * 64];
  __shared__ __align__(16) short Bs[128 * 64];
  const int tid = threadIdx.x, lane = tid & 63;
  const int w = tid >> 6, wr = w >> 1, wc = w & 1;
  const int lo = lane & 15, hi4 = lane >> 4;
  long bRow, bCol;
  gemm_block_map(blockIdx.x, bRow, bCol);
  f32x4 acc[2][4] = {};
  const int nks = K >> 6;
  for (int ks = 0; ks < nks; ++ks) {
#pragma unroll
    for (int i = 0; i < 2; ++i) {
      int c = i * 512 + tid;
      int r = c >> 3;
      int wi = ((c & 7) * 16) ^ ((r & 7) << 4);
      glds16((const char*)A + (bRow + r) * (long)(K * 2) + ks * 128 + wi, (char*)As + c * 16);
      glds16((const char*)B + (bCol + r) * (long)(K * 2) + ks * 128 + wi, (char*)Bs + c * 16);
    }
    __syncthreads();
#pragma unroll
    for (int kk = 0; kk < 2; ++kk) {
      bf16x8 af[2], bfr[4];
#pragma unroll
      for (int m = 0; m < 2; ++m) {
        int r = wr * 32 + m * 16 + lo;
        af[m] = *(const bf16x8*)((const char*)As + r * 128 + ((kk * 64 + hi4 * 16) ^ ((r & 7) << 4)));
      }
#pragma unroll
      for (int n = 0; n < 4; ++n) {
        int r = wc * 64 + n * 16 + lo;
        bfr[n] = *(const bf16x8*)((const char*)Bs + r * 128 + ((kk * 64 + hi4 * 16) ^ ((r & 7) << 4)));
      }
#pragma unroll
      for (int m = 0; m < 2; ++m)
#pragma unroll
        for (int n = 0; n < 4; ++n)
          acc[m][n] = __builtin_amdgcn_mfma_f32_16x16x32_bf16(af[m], bfr[n], acc[m][n], 0, 0, 0);
    }
    __syncthreads();
  }
#pragma unroll
  for (int n = 0; n < 4; ++n) {
    long col = bCol + wc * 64 + n * 16 + lo;
    float bv = bias[col];
#pragma unroll
    for (int m = 0; m < 2; ++m) {
      long row0 = bRow + wr * 32 + m * 16 + hi4 * 4;
#pragma unroll
      for (int j = 0; j < 4; ++j) {
        float v = acc[m][n][j] + bv;
        if (OUT_F32) ((float*)C)[(row0 + j) * N + col] = v;
        else ((short*)C)[(row0 + j) * N + col] = f2bf(v);
      }
    }
  }
}

// ---------------------------------------------------------------------------
// Split-precision NT GEMM: C = (Ahi+Alo)(Bhi+Blo)^T + bias  (3-term MFMA)
// 128x128 tile, BK=64, 8 waves (512 thr), outputs hi/lo bf16.
// ---------------------------------------------------------------------------
__global__ __launch_bounds__(512) void k_gemm_split(
    const short* __restrict__ Ahi, const short* __restrict__ Alo,
    const short* __restrict__ Bhi, const short* __restrict__ Blo,
    const float* __restrict__ bias, short* __restrict__ Chi,
    short* __restrict__ Clo, int M, int N, int K) {
  __shared__ __align__(16) short AsH[128 * 64], AsL[128 * 64];
  __shared__ __align__(16) short BsH[128 * 64], BsL[128 * 64];
  const int tid = threadIdx.x, lane = tid & 63;
  const int w = tid >> 6, wr = w >> 1, wc = w & 1;
  const int lo = lane & 15, hi4 = lane >> 4;
  long bRow, bCol;
  gemm_block_map(blockIdx.x, bRow, bCol);
  f32x4 acc[2][4] = {};
  const int nks = K >> 6;
  for (int ks = 0; ks < nks; ++ks) {
#pragma unroll
    for (int i = 0; i < 2; ++i) {
      int c = i * 512 + tid;
      int r = c >> 3;
      int wi = ((c & 7) * 16) ^ ((r & 7) << 4);
      glds16((const char*)Ahi + (bRow + r) * (long)(K * 2) + ks * 128 + wi, (char*)AsH + c * 16);
      glds16((const char*)Alo + (bRow + r) * (long)(K * 2) + ks * 128 + wi, (char*)AsL + c * 16);
      glds16((const char*)Bhi + (bCol + r) * (long)(K * 2) + ks * 128 + wi, (char*)BsH + c * 16);
      glds16((const char*)Blo + (bCol + r) * (long)(K * 2) + ks * 128 + wi, (char*)BsL + c * 16);
    }
    __syncthreads();
#pragma unroll
    for (int kk = 0; kk < 2; ++kk) {
      bf16x8 ah[2], al[2], bh[4], bl[4];
#pragma unroll
      for (int m = 0; m < 2; ++m) {
        int r = wr * 32 + m * 16 + lo;
        int off = r * 128 + ((kk * 64 + hi4 * 16) ^ ((r & 7) << 4));
        ah[m] = *(const bf16x8*)((const char*)AsH + off);
        al[m] = *(const bf16x8*)((const char*)AsL + off);
      }
#pragma unroll
      for (int n = 0; n < 4; ++n) {
        int r = wc * 64 + n * 16 + lo;
        int off = r * 128 + ((kk * 64 + hi4 * 16) ^ ((r & 7) << 4));
        bh[n] = *(const bf16x8*)((const char*)BsH + off);
        bl[n] = *(const bf16x8*)((const char*)BsL + off);
      }
#pragma unroll
      for (int m = 0; m < 2; ++m)
#pragma unroll
        for (int n = 0; n < 4; ++n) {
          acc[m][n] = __builtin_amdgcn_mfma_f32_16x16x32_bf16(ah[m], bh[n], acc[m][n], 0, 0, 0);
          acc[m][n] = __builtin_amdgcn_mfma_f32_16x16x32_bf16(ah[m], bl[n], acc[m][n], 0, 0, 0);
          acc[m][n] = __builtin_amdgcn_mfma_f32_16x16x32_bf16(al[m], bh[n], acc[m][n], 0, 0, 0);
        }
    }
    __syncthreads();
  }
#pragma unroll
  for (int n = 0; n < 4; ++n) {
    long col = bCol + wc * 64 + n * 16 + lo;
    float bv = bias[col];
#pragma unroll
    for (int m = 0; m < 2; ++m)
#pragma unroll
      for (int j = 0; j < 4; ++j) {
        long row = bRow + wr * 32 + m * 16 + hi4 * 4 + j;
        float v = acc[m][n][j] + bv;
        short h = f2bf(v);
        float res = v - bf2f(h);
        Chi[row * N + col] = h;
        Clo[row * N + col] = f2bf(res);
      }
  }
}

// ---------------------------------------------------------------------------
// Transpose V slices (flat-index transform, PROVEN r1/r2/r5):
// Vb flat [g][1024 t][64 d] -> Vt [g][64 d][1024 t]
// ---------------------------------------------------------------------------
__global__ __launch_bounds__(256) void k_transpose_v(const short* __restrict__ Vb,
                                                     short* __restrict__ Vt) {
  __shared__ __align__(16) short T[64][264];
  int g = blockIdx.y, t0 = blockIdx.x * 256;
  int tid = threadIdx.x;
  const short* src = Vb + (long)g * 65536;
#pragma unroll
  for (int i = 0; i < 8; ++i) {
    int c = i * 256 + tid;  // 0..2047
    int t = c >> 3, dc = (c & 7) * 8;
    bf16x8 v = *(const bf16x8*)(src + (long)(t0 + t) * 64 + dc);
#pragma unroll
    for (int e = 0; e < 8; ++e) T[dc + e][t] = v[e];
  }
  __syncthreads();
  short* dst = Vt + (long)g * 65536;
#pragma unroll
  for (int i = 0; i < 8; ++i) {
    int c = i * 256 + tid;
    int d = c >> 5, tc = (c & 31) * 8;
    bf16x8 v = *(const bf16x8*)(&T[d][tc]);
    *(bf16x8*)(dst + (long)d * 1024 + t0 + tc) = v;
  }
}

// ---------------------------------------------------------------------------
// k_mu: Thr[g,s] = (q_s . sum_t k_t) * NORM / 1024  (analytic row-mean of S)
// ---------------------------------------------------------------------------
__global__ __launch_bounds__(256) void k_mu(
    const short* __restrict__ Khi, const short* __restrict__ Klo,
    const short* __restrict__ Qhi, const short* __restrict__ Qlo,
    float* __restrict__ Thr) {
  __shared__ float tmp[32][64];
  __shared__ float ksum[64];
  const int g = blockIdx.x, tid = threadIdx.x;
  const int d8 = tid & 7, tq = tid >> 3;
  const short* kh = Khi + (long)g * 65536;
  const short* kl = Klo + (long)g * 65536;
  float acc[8] = {};
  for (int t = tq; t < 1024; t += 32) {
    bf16x8 a = *(const bf16x8*)(kh + t * 64 + d8 * 8);
    bf16x8 b = *(const bf16x8*)(kl + t * 64 + d8 * 8);
#pragma unroll
    for (int e = 0; e < 8; ++e) acc[e] += bf2f(a[e]) + bf2f(b[e]);
  }
#pragma unroll
  for (int e = 0; e < 8; ++e) tmp[tq][d8 * 8 + e] = acc[e];
  __syncthreads();
  if (tid < 64) {
    float s = 0.f;
#pragma unroll
    for (int q = 0; q < 32; ++q) s += tmp[q][tid];
    ksum[tid] = s;
  }
  __syncthreads();
  const float c = 0.03125f / 1024.f;
  for (int s = tid; s < 1024; s += 256) {
    const short* qh = Qhi + (long)g * 65536 + s * 64;
    const short* ql = Qlo + (long)g * 65536 + s * 64;
    float dot = 0.f;
#pragma unroll
    for (int d0 = 0; d0 < 64; d0 += 8) {
      bf16x8 a = *(const bf16x8*)(qh + d0);
      bf16x8 b = *(const bf16x8*)(ql + d0);
#pragma unroll
      for (int e = 0; e < 8; ++e) dot += (bf2f(a[e]) + bf2f(b[e])) * ksum[d0 + e];
    }
    Thr[g * 1024 + s] = dot * c;
  }
}

// ---------------------------------------------------------------------------
// Pass A (plain bf16): block owns 64 columns t of one slice; iterates Q tiles.
// rL[t] = 1 / sum_s exp(S_plain[s,t]).
// ---------------------------------------------------------------------------
__global__ __launch_bounds__(256) void k_passA(
    const short* __restrict__ Qhi, const short* __restrict__ Khi,
    float* __restrict__ rL) {
  __shared__ __align__(16) short KsH[64 * 64];
  __shared__ __align__(16) short QsH[64 * 64];
  const int wg = blockIdx.x;
  const int g = (wg & 7) | ((wg >> 7) << 3);  // slice pinned to XCD g&7
  const int tb = (wg >> 3) & 15;
  const int tid = threadIdx.x, lane = tid & 63;
  const int w = tid >> 6;
  const int lo = lane & 15, hi4 = lane >> 4;
  const long gbase = (long)g * 131072;  // bytes
#pragma unroll
  for (int i = 0; i < 2; ++i) {
    int c = i * 256 + tid;
    int r = c >> 3;
    int wi = ((c & 7) * 16) ^ ((r & 7) << 4);
    glds16((const char*)Khi + gbase + (long)(tb * 64 + r) * 128 + wi, (char*)KsH + c * 16);
  }
  __syncthreads();
  bf16x8 kh[2];
#pragma unroll
  for (int kk = 0; kk < 2; ++kk) {
    int r = w * 16 + lo;
    kh[kk] = *(const bf16x8*)((const char*)KsH + r * 128 + ((kk * 64 + hi4 * 16) ^ ((r & 7) << 4)));
  }
  float Lacc[4] = {};
  for (int sb = 0; sb < 16; ++sb) {
#pragma unroll
    for (int i = 0; i < 2; ++i) {
      int c = i * 256 + tid;
      int r = c >> 3;
      int wi = ((c & 7) * 16) ^ ((r & 7) << 4);
      glds16((const char*)Qhi + gbase + (long)(sb * 64 + r) * 128 + wi, (char*)QsH + c * 16);
    }
    __syncthreads();
    f32x4 s[4] = {};
#pragma unroll
    for (int kk = 0; kk < 2; ++kk) {
#pragma unroll
      for (int n = 0; n < 4; ++n) {
        int r = n * 16 + lo;
        bf16x8 qf = *(const bf16x8*)((const char*)QsH + r * 128 +
                                     ((kk * 64 + hi4 * 16) ^ ((r & 7) << 4)));
        __builtin_amdgcn_s_setprio(1);
        s[n] = __builtin_amdgcn_mfma_f32_16x16x32_bf16(kh[kk], qf, s[n], 0, 0, 0);
        __builtin_amdgcn_s_setprio(0);
      }
    }
#pragma unroll
    for (int n = 0; n < 4; ++n)
#pragma unroll
      for (int j = 0; j < 4; ++j)
        Lacc[j] += __expf(s[n][j] * 0.03125f);
    __syncthreads();
  }
#pragma unroll
  for (int j = 0; j < 4; ++j) {
    float v = Lacc[j];
    v += __shfl_xor(v, 1);
    v += __shfl_xor(v, 2);
    v += __shfl_xor(v, 4);
    v += __shfl_xor(v, 8);
    if (lo == 0) rL[g * 1024 + tb * 64 + w * 16 + hi4 * 4 + j] = 1.0f / v;
  }
}

// ---------------------------------------------------------------------------
// Pass B: S^T via swapped-operand split MFMA. VALU-lean softmax phase:
// - e = exp2(s * (2^-5 * log2 e)) via __builtin_amdgcn_exp2f (raw v_exp_f32)
// - mask compare on raw s vs thre*32 (exact: power-of-two scaling)
// - v_cvt_pk_bf16_f32 packing (round-4 A/B proved bit-equivalence to
//   the software RNE pack on this data)
// - R/Z accumulate UNROUNDED p1/p2 (perturbation <=2e-5, margin 4.6x)
// ---------------------------------------------------------------------------
__global__ __launch_bounds__(256, 4) void k_passB(
    const short* __restrict__ Qhi, const short* __restrict__ Qlo,
    const short* __restrict__ Khi, const short* __restrict__ Klo,
    const short* __restrict__ Vt, const float* __restrict__ rL,
    const float* __restrict__ Thr, short* __restrict__ Pre,
    const int* __restrict__ rmask) {
  __shared__ __align__(16) short KsH[64 * 64], KsL[64 * 64];
  __shared__ __align__(16) short Vs[64 * 64];
  __shared__ __align__(16) short Ps1[64 * 64], Ps2[64 * 64];
  const int wg = blockIdx.x;
  const int g = (wg & 7) | ((wg >> 7) << 3);
  const int rb = (wg >> 3) & 15;
  const int tid = threadIdx.x, lane = tid & 63;
  const int w = tid >> 6;
  const int lo = lane & 15, hi4 = lane >> 4;
  const long gbase = (long)g * 131072;
  const bool use_mask = (*rmask != 0);
  const int srow = w * 16 + lo;  // this thread's block-local s row
  bf16x8 qfh[2], qfl[2];
  {
    const char* qrh = (const char*)Qhi + gbase + (long)(rb * 64 + srow) * 128;
    const char* qrl = (const char*)Qlo + gbase + (long)(rb * 64 + srow) * 128;
#pragma unroll
    for (int kk = 0; kk < 2; ++kk) {
      qfh[kk] = *(const bf16x8*)(qrh + kk * 64 + hi4 * 16);
      qfl[kk] = *(const bf16x8*)(qrl + kk * 64 + hi4 * 16);
    }
  }
  // exact power-of-two rescale: s*2^-5 > thre  <=>  s > thre*32
  const float thre32 = use_mask ? Thr[g * 1024 + rb * 64 + srow] * 32.0f : -3.4e38f;
  const float CEXP = 0.045136860026163146f;  // 2^-5 * log2(e)
  float rpart = 0.f, zpart = 0.f;
  f32x4 o1[4] = {}, o2[4] = {};

  for (int tb = 0; tb < 16; ++tb) {
#pragma unroll
    for (int i = 0; i < 2; ++i) {
      int c = i * 256 + tid;
      int r = c >> 3;
      int wi = ((c & 7) * 16) ^ ((r & 7) << 4);
      glds16((const char*)Khi + gbase + (long)(tb * 64 + r) * 128 + wi, (char*)KsH + c * 16);
      glds16((const char*)Klo + gbase + (long)(tb * 64 + r) * 128 + wi, (char*)KsL + c * 16);
      glds16((const char*)Vt + gbase + (long)r * 2048 + tb * 128 + wi, (char*)Vs + c * 16);
    }
    __syncthreads();
    // --- S^T = K.Q^T (split, 24 MFMA/wave): lane -> t = n*16+hi4*4+j, s = srow
    f32x4 s[4] = {};
#pragma unroll
    for (int kk = 0; kk < 2; ++kk) {
#pragma unroll
      for (int n = 0; n < 4; ++n) {
        int r = n * 16 + lo;
        int off = r * 128 + ((kk * 64 + hi4 * 16) ^ ((r & 7) << 4));
        bf16x8 kh = *(const bf16x8*)((const char*)KsH + off);
        bf16x8 kl = *(const bf16x8*)((const char*)KsL + off);
        __builtin_amdgcn_s_setprio(1);
        s[n] = __builtin_amdgcn_mfma_f32_16x16x32_bf16(kh, qfh[kk], s[n], 0, 0, 0);
        s[n] = __builtin_amdgcn_mfma_f32_16x16x32_bf16(kh, qfl[kk], s[n], 0, 0, 0);
        s[n] = __builtin_amdgcn_mfma_f32_16x16x32_bf16(kl, qfh[kk], s[n], 0, 0, 0);
        __builtin_amdgcn_s_setprio(0);
      }
    }
    // --- softmax pieces + dual P-store (cvt_pk, unrounded R/Z) ---
#pragma unroll
    for (int n = 0; n < 4; ++n) {
      const float4 rl4 = *(const float4*)(rL + g * 1024 + tb * 64 + n * 16 + hi4 * 4);
      const float* rlp = (const float*)&rl4;
      float p1v[4], p2v[4];
#pragma unroll
      for (int j = 0; j < 4; ++j) {
        float sraw = s[n][j];
        float e = __builtin_amdgcn_exp2f(sraw * CEXP);
        float p1 = e * rlp[j];
        float p2 = (sraw > thre32) ? e : 0.f;
        p1v[j] = p1;
        p2v[j] = p2;
        rpart += p1;
        zpart += p2;
      }
      unsigned u10, u11, u20, u21;
      asm("v_cvt_pk_bf16_f32 %0, %1, %2" : "=v"(u10) : "v"(p1v[0]), "v"(p1v[1]));
      asm("v_cvt_pk_bf16_f32 %0, %1, %2" : "=v"(u11) : "v"(p1v[2]), "v"(p1v[3]));
      asm("v_cvt_pk_bf16_f32 %0, %1, %2" : "=v"(u20) : "v"(p2v[0]), "v"(p2v[1]));
      asm("v_cvt_pk_bf16_f32 %0, %1, %2" : "=v"(u21) : "v"(p2v[2]), "v"(p2v[3]));
      int colb = n * 32 + hi4 * 8;
      int boff = srow * 128 + (colb ^ ((srow & 7) << 4));
      uint2 w1; w1.x = u10; w1.y = u11;
      uint2 w2; w2.x = u20; w2.y = u21;
      *(uint2*)((char*)Ps1 + boff) = w1;
      *(uint2*)((char*)Ps2 + boff) = w2;
    }
    __syncthreads();
    // --- merged dual PV (16 MFMA/wave) ---
#pragma unroll
    for (int kk = 0; kk < 2; ++kk) {
      int poff = srow * 128 + ((kk * 64 + hi4 * 16) ^ ((srow & 7) << 4));
      bf16x8 pa1 = *(const bf16x8*)((const char*)Ps1 + poff);
      bf16x8 pa2 = *(const bf16x8*)((const char*)Ps2 + poff);
#pragma unroll
      for (int n = 0; n < 4; ++n) {
        int d = n * 16 + lo;
        bf16x8 vb = *(const bf16x8*)((const char*)Vs + d * 128 +
                                     ((kk * 64 + hi4 * 16) ^ ((d & 7) << 4)));
        __builtin_amdgcn_s_setprio(1);
        o1[n] = __builtin_amdgcn_mfma_f32_16x16x32_bf16(pa1, vb, o1[n], 0, 0, 0);
        o2[n] = __builtin_amdgcn_mfma_f32_16x16x32_bf16(pa2, vb, o2[n], 0, 0, 0);
        __builtin_amdgcn_s_setprio(0);
      }
    }
    __syncthreads();
  }
  // --- row sums: reduce over the 4 hi4 t-quarters, redistribute via LDS ---
  float r = rpart;
  r += __shfl_xor(r, 16);
  r += __shfl_xor(r, 32);
  float z = zpart;
  z += __shfl_xor(z, 16);
  z += __shfl_xor(z, 32);
  float* Rbuf = (float*)Ps1;
  float* Zbuf = (float*)Ps2;
  if (hi4 == 0) { Rbuf[srow] = r; Zbuf[srow] = z; }
  __syncthreads();
#pragma unroll
  for (int n = 0; n < 4; ++n)
#pragma unroll
    for (int j = 0; j < 4; ++j) {
      int rl_ = w * 16 + hi4 * 4 + j;
      float rr = fmaxf(Rbuf[rl_], 1e-12f);
      float zz = fmaxf(Zbuf[rl_], 1e-30f);
      float val = 0.5f * (o1[n][j] / rr + o2[n][j] / zz);
      Pre[(long)g * 65536 + (long)(rb * 64 + rl_) * 64 + n * 16 + lo] = f2bf(val);
    }
}

// ---------------------------------------------------------------------------
extern "C" void kernel_launch(void* const* d_in, const int* in_sizes, int n_in,
                              void* d_out, int out_size, void* d_ws, size_t ws_size,
                              hipStream_t stream) {
  const float* x  = (const float*)d_in[0];
  const float* y  = (const float*)d_in[1];
  const float* Wq = (const float*)d_in[2];
  const float* bq = (const float*)d_in[3];
  const float* Wk = (const float*)d_in[4];
  const float* bk = (const float*)d_in[5];
  const float* Wv = (const float*)d_in[6];
  const float* bv = (const float*)d_in[7];
  const float* Wo = (const float*)d_in[8];
  const float* bo = (const float*)d_in[9];
  const int* rm   = (const int*)d_in[10];
  float* out = (float*)d_out;

  char* ws = (char*)d_ws;
  size_t off = 0;
  auto alloc = [&](size_t bytes) {
    char* p = ws + off;
    off += (bytes + 255) & ~(size_t)255;
    return p;
  };
  short* xhi  = (short*)alloc(4194304 * 2);
  short* xlo  = (short*)alloc(4194304 * 2);
  short* yhi  = (short*)alloc(4194304 * 2);
  short* ylo  = (short*)alloc(4194304 * 2);
  short* wqhi = (short*)alloc(1048576 * 2);
  short* wqlo = (short*)alloc(1048576 * 2);
  short* wkhi = (short*)alloc(1048576 * 2);
  short* wklo = (short*)alloc(1048576 * 2);
  short* wvhi = (short*)alloc(1048576 * 2);
  short* wohi = (short*)alloc(1048576 * 2);
  short* QhiB = (short*)alloc(4194304 * 2);
  short* QloB = (short*)alloc(4194304 * 2);
  short* KhiB = (short*)alloc(4194304 * 2);
  short* KloB = (short*)alloc(4194304 * 2);
  short* Vb   = (short*)alloc(4194304 * 2);
  short* VtB  = (short*)alloc(4194304 * 2);
  short* pre  = (short*)alloc(4194304 * 2);
  float* rLbuf = (float*)alloc(65536 * 4);
  float* Thr   = (float*)alloc(65536 * 4);
  if (off > ws_size) return;

  k_convert<<<dim3(4096, 6), 256, 0, stream>>>(x, y, Wq, Wk, Wv, Wo, xhi, xlo, yhi, ylo,
                                               wqhi, wqlo, wkhi, wklo, wvhi, wohi);

  k_gemm_split<<<256, 512, 0, stream>>>(xhi, xlo, wqhi, wqlo, bq, QhiB, QloB,
                                        4096, 1024, 1024);
  k_gemm_split<<<256, 512, 0, stream>>>(yhi, ylo, wkhi, wklo, bk, KhiB, KloB,
                                        4096, 1024, 1024);
  k_gemm_plain<0><<<256, 512, 0, stream>>>(yhi, wvhi, bv, Vb, 4096, 1024, 1024);
  k_transpose_v<<<dim3(4, 64), 256, 0, stream>>>(Vb, VtB);
  k_mu<<<64, 256, 0, stream>>>(KhiB, KloB, QhiB, QloB, Thr);
  k_passA<<<1024, 256, 0, stream>>>(QhiB, KhiB, rLbuf);
  k_passB<<<1024, 256, 0, stream>>>(QhiB, QloB, KhiB, KloB, VtB, rLbuf, Thr, pre, rm);
  k_gemm_plain<1><<<256, 512, 0, stream>>>(pre, wohi, bo, out, 4096, 1024, 1024);
}

// Round 8
// 187.660 us; speedup vs baseline: 1.4574x; 1.1764x over previous
//
#include <hip/hip_runtime.h>
#include <hip/hip_bf16.h>
#include <stdint.h>

typedef float f32x4 __attribute__((ext_vector_type(4)));
typedef short bf16x8 __attribute__((ext_vector_type(8)));
typedef _Float16 f16x8 __attribute__((ext_vector_type(8)));

#define DEV static __device__ __forceinline__

DEV float bf2f(short u) {
  union { float f; unsigned i; } v;
  v.i = ((unsigned)(unsigned short)u) << 16;
  return v.f;
}
DEV short f2bf(float f) {
  union { float f; unsigned i; } v;
  v.f = f;
  unsigned lsb = (v.i >> 16) & 1u;
  v.i += 0x7fffu + lsb;
  return (short)(v.i >> 16);
}
DEV short f2h(float f) {
  union { _Float16 h; short s; } u;
  u.h = (_Float16)f;
  return u.s;
}

DEV void glds16(const void* g, void* l) {
  __builtin_amdgcn_global_load_lds(
      (const __attribute__((address_space(1))) void*)g,
      (__attribute__((address_space(3))) void*)l, 16, 0, 0);
}

// ---------------------------------------------------------------------------
// Convert fp32 -> fp16 (x, y, Wq, Wk, Wv) and bf16 (Wo)
// ---------------------------------------------------------------------------
__global__ __launch_bounds__(256) void k_convert(
    const float* __restrict__ x, const float* __restrict__ y,
    const float* __restrict__ wq, const float* __restrict__ wk,
    const float* __restrict__ wv, const float* __restrict__ wo,
    short* __restrict__ x16, short* __restrict__ y16,
    short* __restrict__ wq16, short* __restrict__ wk16,
    short* __restrict__ wv16, short* __restrict__ wohi) {
  const float* src; short* dst; int n, half;
  switch (blockIdx.y) {
    case 0: src = x;  dst = x16;  n = 4194304; half = 1; break;
    case 1: src = y;  dst = y16;  n = 4194304; half = 1; break;
    case 2: src = wq; dst = wq16; n = 1048576; half = 1; break;
    case 3: src = wk; dst = wk16; n = 1048576; half = 1; break;
    case 4: src = wv; dst = wv16; n = 1048576; half = 1; break;
    default: src = wo; dst = wohi; n = 1048576; half = 0; break;
  }
  int i4 = blockIdx.x * 256 + threadIdx.x;
  if (i4 * 4 >= n) return;
  float4 v = ((const float4*)src)[i4];
  short4 h;
  float* pv = (float*)&v;
  short* ph = (short*)&h;
#pragma unroll
  for (int e = 0; e < 4; ++e) ph[e] = half ? f2h(pv[e]) : f2bf(pv[e]);
  ((short4*)dst)[i4] = h;
}

// ---------------------------------------------------------------------------
// XCD-pinned block remap for M=4096(32 row-panels) x N=1024(8 col-blocks)
// ---------------------------------------------------------------------------
DEV void gemm_block_map(int wg, long& bRow, long& bCol) {
  int rlow = wg & 7, c = (wg >> 3) & 7, rhigh = wg >> 6;
  bRow = (long)(rhigh * 8 + rlow) * 128;
  bCol = (long)c * 128;
}

// ---------------------------------------------------------------------------
// Plain bf16 NT GEMM with bias (used for the Wo output projection only).
// ---------------------------------------------------------------------------
__global__ __launch_bounds__(512) void k_gemm_out(
    const short* __restrict__ A, const short* __restrict__ B,
    const float* __restrict__ bias, float* __restrict__ C, int M, int N, int K) {
  __shared__ __align__(16) short As[128 * 64];
  __shared__ __align__(16) short Bs[128 * 64];
  const int tid = threadIdx.x, lane = tid & 63;
  const int w = tid >> 6, wr = w >> 1, wc = w & 1;
  const int lo = lane & 15, hi4 = lane >> 4;
  long bRow, bCol;
  gemm_block_map(blockIdx.x, bRow, bCol);
  f32x4 acc[2][4] = {};
  const int nks = K >> 6;
  for (int ks = 0; ks < nks; ++ks) {
#pragma unroll
    for (int i = 0; i < 2; ++i) {
      int c = i * 512 + tid;
      int r = c >> 3;
      int wi = ((c & 7) * 16) ^ ((r & 7) << 4);
      glds16((const char*)A + (bRow + r) * (long)(K * 2) + ks * 128 + wi, (char*)As + c * 16);
      glds16((const char*)B + (bCol + r) * (long)(K * 2) + ks * 128 + wi, (char*)Bs + c * 16);
    }
    __syncthreads();
#pragma unroll
    for (int kk = 0; kk < 2; ++kk) {
      bf16x8 af[2], bfr[4];
#pragma unroll
      for (int m = 0; m < 2; ++m) {
        int r = wr * 32 + m * 16 + lo;
        af[m] = *(const bf16x8*)((const char*)As + r * 128 + ((kk * 64 + hi4 * 16) ^ ((r & 7) << 4)));
      }
#pragma unroll
      for (int n = 0; n < 4; ++n) {
        int r = wc * 64 + n * 16 + lo;
        bfr[n] = *(const bf16x8*)((const char*)Bs + r * 128 + ((kk * 64 + hi4 * 16) ^ ((r & 7) << 4)));
      }
#pragma unroll
      for (int m = 0; m < 2; ++m)
#pragma unroll
        for (int n = 0; n < 4; ++n)
          acc[m][n] = __builtin_amdgcn_mfma_f32_16x16x32_bf16(af[m], bfr[n], acc[m][n], 0, 0, 0);
    }
    __syncthreads();
  }
#pragma unroll
  for (int n = 0; n < 4; ++n) {
    long col = bCol + wc * 64 + n * 16 + lo;
    float bv = bias[col];
#pragma unroll
    for (int m = 0; m < 2; ++m) {
      long row0 = bRow + wr * 32 + m * 16 + hi4 * 4;
#pragma unroll
      for (int j = 0; j < 4; ++j)
        C[(row0 + j) * N + col] = acc[m][n][j] + bv;
    }
  }
}

// ---------------------------------------------------------------------------
// fp16 NT GEMM with bias. OUT_SPLIT=1: bf16 hi/lo outputs (Q/K projections).
// OUT_SPLIT=0: single bf16 output (V projection).
// ---------------------------------------------------------------------------
template <int OUT_SPLIT>
__global__ __launch_bounds__(512) void k_gemm_f16(
    const short* __restrict__ A, const short* __restrict__ B,
    const float* __restrict__ bias, short* __restrict__ Chi,
    short* __restrict__ Clo, int M, int N, int K) {
  __shared__ __align__(16) short As[128 * 64];
  __shared__ __align__(16) short Bs[128 * 64];
  const int tid = threadIdx.x, lane = tid & 63;
  const int w = tid >> 6, wr = w >> 1, wc = w & 1;
  const int lo = lane & 15, hi4 = lane >> 4;
  long bRow, bCol;
  gemm_block_map(blockIdx.x, bRow, bCol);
  f32x4 acc[2][4] = {};
  const int nks = K >> 6;
  for (int ks = 0; ks < nks; ++ks) {
#pragma unroll
    for (int i = 0; i < 2; ++i) {
      int c = i * 512 + tid;
      int r = c >> 3;
      int wi = ((c & 7) * 16) ^ ((r & 7) << 4);
      glds16((const char*)A + (bRow + r) * (long)(K * 2) + ks * 128 + wi, (char*)As + c * 16);
      glds16((const char*)B + (bCol + r) * (long)(K * 2) + ks * 128 + wi, (char*)Bs + c * 16);
    }
    __syncthreads();
#pragma unroll
    for (int kk = 0; kk < 2; ++kk) {
      f16x8 af[2], bfr[4];
#pragma unroll
      for (int m = 0; m < 2; ++m) {
        int r = wr * 32 + m * 16 + lo;
        af[m] = *(const f16x8*)((const char*)As + r * 128 + ((kk * 64 + hi4 * 16) ^ ((r & 7) << 4)));
      }
#pragma unroll
      for (int n = 0; n < 4; ++n) {
        int r = wc * 64 + n * 16 + lo;
        bfr[n] = *(const f16x8*)((const char*)Bs + r * 128 + ((kk * 64 + hi4 * 16) ^ ((r & 7) << 4)));
      }
#pragma unroll
      for (int m = 0; m < 2; ++m)
#pragma unroll
        for (int n = 0; n < 4; ++n)
          acc[m][n] = __builtin_amdgcn_mfma_f32_16x16x32_f16(af[m], bfr[n], acc[m][n], 0, 0, 0);
    }
    __syncthreads();
  }
#pragma unroll
  for (int n = 0; n < 4; ++n) {
    long col = bCol + wc * 64 + n * 16 + lo;
    float bv = bias[col];
#pragma unroll
    for (int m = 0; m < 2; ++m)
#pragma unroll
      for (int j = 0; j < 4; ++j) {
        long row = bRow + wr * 32 + m * 16 + hi4 * 4 + j;
        float v = acc[m][n][j] + bv;
        short h = f2bf(v);
        Chi[row * N + col] = h;
        if (OUT_SPLIT) Clo[row * N + col] = f2bf(v - bf2f(h));
      }
  }
}

// ---------------------------------------------------------------------------
// Transpose V slices: Vb flat [g][1024 t][64 d] -> Vt [g][64 d][1024 t]
// ---------------------------------------------------------------------------
__global__ __launch_bounds__(256) void k_transpose_v(const short* __restrict__ Vb,
                                                     short* __restrict__ Vt) {
  __shared__ __align__(16) short T[64][264];
  int g = blockIdx.y, t0 = blockIdx.x * 256;
  int tid = threadIdx.x;
  const short* src = Vb + (long)g * 65536;
#pragma unroll
  for (int i = 0; i < 8; ++i) {
    int c = i * 256 + tid;
    int t = c >> 3, dc = (c & 7) * 8;
    bf16x8 v = *(const bf16x8*)(src + (long)(t0 + t) * 64 + dc);
#pragma unroll
    for (int e = 0; e < 8; ++e) T[dc + e][t] = v[e];
  }
  __syncthreads();
  short* dst = Vt + (long)g * 65536;
#pragma unroll
  for (int i = 0; i < 8; ++i) {
    int c = i * 256 + tid;
    int d = c >> 5, tc = (c & 31) * 8;
    bf16x8 v = *(const bf16x8*)(&T[d][tc]);
    *(bf16x8*)(dst + (long)d * 1024 + t0 + tc) = v;
  }
}

// ---------------------------------------------------------------------------
// k_mu: Thr[g,s] = (q_s . sum_t k_t) * NORM / 1024.  4 blocks per slice.
// ---------------------------------------------------------------------------
__global__ __launch_bounds__(256) void k_mu(
    const short* __restrict__ Khi, const short* __restrict__ Klo,
    const short* __restrict__ Qhi, const short* __restrict__ Qlo,
    float* __restrict__ Thr) {
  __shared__ float tmp[32][64];
  __shared__ float ksum[64];
  const int g = blockIdx.x >> 2, q = blockIdx.x & 3;
  const int tid = threadIdx.x;
  const int d8 = tid & 7, tq = tid >> 3;
  const short* kh = Khi + (long)g * 65536;
  const short* kl = Klo + (long)g * 65536;
  float acc[8] = {};
  for (int t = tq; t < 1024; t += 32) {
    bf16x8 a = *(const bf16x8*)(kh + t * 64 + d8 * 8);
    bf16x8 b = *(const bf16x8*)(kl + t * 64 + d8 * 8);
#pragma unroll
    for (int e = 0; e < 8; ++e) acc[e] += bf2f(a[e]) + bf2f(b[e]);
  }
#pragma unroll
  for (int e = 0; e < 8; ++e) tmp[tq][d8 * 8 + e] = acc[e];
  __syncthreads();
  if (tid < 64) {
    float s = 0.f;
#pragma unroll
    for (int qq = 0; qq < 32; ++qq) s += tmp[qq][tid];
    ksum[tid] = s;
  }
  __syncthreads();
  const float c = 0.03125f / 1024.f;
  const int s = q * 256 + tid;
  const short* qh = Qhi + (long)g * 65536 + s * 64;
  const short* ql = Qlo + (long)g * 65536 + s * 64;
  float dot = 0.f;
#pragma unroll
  for (int d0 = 0; d0 < 64; d0 += 8) {
    bf16x8 a = *(const bf16x8*)(qh + d0);
    bf16x8 b = *(const bf16x8*)(ql + d0);
#pragma unroll
    for (int e = 0; e < 8; ++e) dot += (bf2f(a[e]) + bf2f(b[e])) * ksum[d0 + e];
  }
  Thr[g * 1024 + s] = dot * c;
}

// ---------------------------------------------------------------------------
// Pass A (plain bf16): block owns 64 columns t; iterates Q tiles.
// ---------------------------------------------------------------------------
__global__ __launch_bounds__(256) void k_passA(
    const short* __restrict__ Qhi, const short* __restrict__ Khi,
    float* __restrict__ rL) {
  __shared__ __align__(16) short KsH[64 * 64];
  __shared__ __align__(16) short QsH[64 * 64];
  const int wg = blockIdx.x;
  const int g = (wg & 7) | ((wg >> 7) << 3);
  const int tb = (wg >> 3) & 15;
  const int tid = threadIdx.x, lane = tid & 63;
  const int w = tid >> 6;
  const int lo = lane & 15, hi4 = lane >> 4;
  const long gbase = (long)g * 131072;
#pragma unroll
  for (int i = 0; i < 2; ++i) {
    int c = i * 256 + tid;
    int r = c >> 3;
    int wi = ((c & 7) * 16) ^ ((r & 7) << 4);
    glds16((const char*)Khi + gbase + (long)(tb * 64 + r) * 128 + wi, (char*)KsH + c * 16);
  }
  __syncthreads();
  bf16x8 kh[2];
#pragma unroll
  for (int kk = 0; kk < 2; ++kk) {
    int r = w * 16 + lo;
    kh[kk] = *(const bf16x8*)((const char*)KsH + r * 128 + ((kk * 64 + hi4 * 16) ^ ((r & 7) << 4)));
  }
  float Lacc[4] = {};
  for (int sb = 0; sb < 16; ++sb) {
#pragma unroll
    for (int i = 0; i < 2; ++i) {
      int c = i * 256 + tid;
      int r = c >> 3;
      int wi = ((c & 7) * 16) ^ ((r & 7) << 4);
      glds16((const char*)Qhi + gbase + (long)(sb * 64 + r) * 128 + wi, (char*)QsH + c * 16);
    }
    __syncthreads();
    f32x4 s[4] = {};
#pragma unroll
    for (int kk = 0; kk < 2; ++kk) {
#pragma unroll
      for (int n = 0; n < 4; ++n) {
        int r = n * 16 + lo;
        bf16x8 qf = *(const bf16x8*)((const char*)QsH + r * 128 +
                                     ((kk * 64 + hi4 * 16) ^ ((r & 7) << 4)));
        __builtin_amdgcn_s_setprio(1);
        s[n] = __builtin_amdgcn_mfma_f32_16x16x32_bf16(kh[kk], qf, s[n], 0, 0, 0);
        __builtin_amdgcn_s_setprio(0);
      }
    }
#pragma unroll
    for (int n = 0; n < 4; ++n)
#pragma unroll
      for (int j = 0; j < 4; ++j)
        Lacc[j] += __expf(s[n][j] * 0.03125f);
    __syncthreads();
  }
#pragma unroll
  for (int j = 0; j < 4; ++j) {
    float v = Lacc[j];
    v += __shfl_xor(v, 1);
    v += __shfl_xor(v, 2);
    v += __shfl_xor(v, 4);
    v += __shfl_xor(v, 8);
    if (lo == 0) rL[g * 1024 + tb * 64 + w * 16 + hi4 * 4 + j] = 1.0f / v;
  }
}

// ---------------------------------------------------------------------------
// Pass B: round-7 numerics, P-store -> PV barrier removed (intra-wave dep).
// ---------------------------------------------------------------------------
__global__ __launch_bounds__(256, 4) void k_passB(
    const short* __restrict__ Qhi, const short* __restrict__ Qlo,
    const short* __restrict__ Khi, const short* __restrict__ Klo,
    const short* __restrict__ Vt, const float* __restrict__ rL,
    const float* __restrict__ Thr, short* __restrict__ Pre,
    const int* __restrict__ rmask) {
  __shared__ __align__(16) short KsH[64 * 64], KsL[64 * 64];
  __shared__ __align__(16) short Vs[64 * 64];
  __shared__ __align__(16) short Ps1[64 * 64], Ps2[64 * 64];
  const int wg = blockIdx.x;
  const int g = (wg & 7) | ((wg >> 7) << 3);
  const int rb = (wg >> 3) & 15;
  const int tid = threadIdx.x, lane = tid & 63;
  const int w = tid >> 6;
  const int lo = lane & 15, hi4 = lane >> 4;
  const long gbase = (long)g * 131072;
  const bool use_mask = (*rmask != 0);
  const int srow = w * 16 + lo;
  bf16x8 qfh[2], qfl[2];
  {
    const char* qrh = (const char*)Qhi + gbase + (long)(rb * 64 + srow) * 128;
    const char* qrl = (const char*)Qlo + gbase + (long)(rb * 64 + srow) * 128;
#pragma unroll
    for (int kk = 0; kk < 2; ++kk) {
      qfh[kk] = *(const bf16x8*)(qrh + kk * 64 + hi4 * 16);
      qfl[kk] = *(const bf16x8*)(qrl + kk * 64 + hi4 * 16);
    }
  }
  const float thre32 = use_mask ? Thr[g * 1024 + rb * 64 + srow] * 32.0f : -3.4e38f;
  const float CEXP = 0.045136860026163146f;  // 2^-5 * log2(e)
  float rpart = 0.f, zpart = 0.f;
  f32x4 o1[4] = {}, o2[4] = {};

  for (int tb = 0; tb < 16; ++tb) {
#pragma unroll
    for (int i = 0; i < 2; ++i) {
      int c = i * 256 + tid;
      int r = c >> 3;
      int wi = ((c & 7) * 16) ^ ((r & 7) << 4);
      glds16((const char*)Khi + gbase + (long)(tb * 64 + r) * 128 + wi, (char*)KsH + c * 16);
      glds16((const char*)Klo + gbase + (long)(tb * 64 + r) * 128 + wi, (char*)KsL + c * 16);
      glds16((const char*)Vt + gbase + (long)r * 2048 + tb * 128 + wi, (char*)Vs + c * 16);
    }
    __syncthreads();
    f32x4 s[4] = {};
#pragma unroll
    for (int kk = 0; kk < 2; ++kk) {
#pragma unroll
      for (int n = 0; n < 4; ++n) {
        int r = n * 16 + lo;
        int off = r * 128 + ((kk * 64 + hi4 * 16) ^ ((r & 7) << 4));
        bf16x8 kh = *(const bf16x8*)((const char*)KsH + off);
        bf16x8 kl = *(const bf16x8*)((const char*)KsL + off);
        __builtin_amdgcn_s_setprio(1);
        s[n] = __builtin_amdgcn_mfma_f32_16x16x32_bf16(kh, qfh[kk], s[n], 0, 0, 0);
        s[n] = __builtin_amdgcn_mfma_f32_16x16x32_bf16(kh, qfl[kk], s[n], 0, 0, 0);
        s[n] = __builtin_amdgcn_mfma_f32_16x16x32_bf16(kl, qfh[kk], s[n], 0, 0, 0);
        __builtin_amdgcn_s_setprio(0);
      }
    }
#pragma unroll
    for (int n = 0; n < 4; ++n) {
      const float4 rl4 = *(const float4*)(rL + g * 1024 + tb * 64 + n * 16 + hi4 * 4);
      const float* rlp = (const float*)&rl4;
      float p1v[4], p2v[4];
#pragma unroll
      for (int j = 0; j < 4; ++j) {
        float sraw = s[n][j];
        float e = __builtin_amdgcn_exp2f(sraw * CEXP);
        float p1 = e * rlp[j];
        float p2 = (sraw > thre32) ? e : 0.f;
        p1v[j] = p1;
        p2v[j] = p2;
        rpart += p1;
        zpart += p2;
      }
      unsigned u10, u11, u20, u21;
      asm("v_cvt_pk_bf16_f32 %0, %1, %2" : "=v"(u10) : "v"(p1v[0]), "v"(p1v[1]));
      asm("v_cvt_pk_bf16_f32 %0, %1, %2" : "=v"(u11) : "v"(p1v[2]), "v"(p1v[3]));
      asm("v_cvt_pk_bf16_f32 %0, %1, %2" : "=v"(u20) : "v"(p2v[0]), "v"(p2v[1]));
      asm("v_cvt_pk_bf16_f32 %0, %1, %2" : "=v"(u21) : "v"(p2v[2]), "v"(p2v[3]));
      int colb = n * 32 + hi4 * 8;
      int boff = srow * 128 + (colb ^ ((srow & 7) << 4));
      uint2 w1; w1.x = u10; w1.y = u11;
      uint2 w2; w2.x = u20; w2.y = u21;
      *(uint2*)((char*)Ps1 + boff) = w1;
      *(uint2*)((char*)Ps2 + boff) = w2;
    }
    // no barrier: each wave reads back only its own 16 P rows (intra-wave)
#pragma unroll
    for (int kk = 0; kk < 2; ++kk) {
      int poff = srow * 128 + ((kk * 64 + hi4 * 16) ^ ((srow & 7) << 4));
      bf16x8 pa1 = *(const bf16x8*)((const char*)Ps1 + poff);
      bf16x8 pa2 = *(const bf16x8*)((const char*)Ps2 + poff);
#pragma unroll
      for (int n = 0; n < 4; ++n) {
        int d = n * 16 + lo;
        bf16x8 vb = *(const bf16x8*)((const char*)Vs + d * 128 +
                                     ((kk * 64 + hi4 * 16) ^ ((d & 7) << 4)));
        __builtin_amdgcn_s_setprio(1);
        o1[n] = __builtin_amdgcn_mfma_f32_16x16x32_bf16(pa1, vb, o1[n], 0, 0, 0);
        o2[n] = __builtin_amdgcn_mfma_f32_16x16x32_bf16(pa2, vb, o2[n], 0, 0, 0);
        __builtin_amdgcn_s_setprio(0);
      }
    }
    __syncthreads();
  }
  float r = rpart;
  r += __shfl_xor(r, 16);
  r += __shfl_xor(r, 32);
  float z = zpart;
  z += __shfl_xor(z, 16);
  z += __shfl_xor(z, 32);
  float* Rbuf = (float*)Ps1;
  float* Zbuf = (float*)Ps2;
  if (hi4 == 0) { Rbuf[srow] = r; Zbuf[srow] = z; }
  __syncthreads();
#pragma unroll
  for (int n = 0; n < 4; ++n)
#pragma unroll
    for (int j = 0; j < 4; ++j) {
      int rl_ = w * 16 + hi4 * 4 + j;
      float rr = fmaxf(Rbuf[rl_], 1e-12f);
      float zz = fmaxf(Zbuf[rl_], 1e-30f);
      float val = 0.5f * (o1[n][j] / rr + o2[n][j] / zz);
      Pre[(long)g * 65536 + (long)(rb * 64 + rl_) * 64 + n * 16 + lo] = f2bf(val);
    }
}

// ---------------------------------------------------------------------------
extern "C" void kernel_launch(void* const* d_in, const int* in_sizes, int n_in,
                              void* d_out, int out_size, void* d_ws, size_t ws_size,
                              hipStream_t stream) {
  const float* x  = (const float*)d_in[0];
  const float* y  = (const float*)d_in[1];
  const float* Wq = (const float*)d_in[2];
  const float* bq = (const float*)d_in[3];
  const float* Wk = (const float*)d_in[4];
  const float* bk = (const float*)d_in[5];
  const float* Wv = (const float*)d_in[6];
  const float* bv = (const float*)d_in[7];
  const float* Wo = (const float*)d_in[8];
  const float* bo = (const float*)d_in[9];
  const int* rm   = (const int*)d_in[10];
  float* out = (float*)d_out;

  char* ws = (char*)d_ws;
  size_t off = 0;
  auto alloc = [&](size_t bytes) {
    char* p = ws + off;
    off += (bytes + 255) & ~(size_t)255;
    return p;
  };
  short* x16  = (short*)alloc(4194304 * 2);
  short* y16  = (short*)alloc(4194304 * 2);
  short* wq16 = (short*)alloc(1048576 * 2);
  short* wk16 = (short*)alloc(1048576 * 2);
  short* wv16 = (short*)alloc(1048576 * 2);
  short* wohi = (short*)alloc(1048576 * 2);
  short* QhiB = (short*)alloc(4194304 * 2);
  short* QloB = (short*)alloc(4194304 * 2);
  short* KhiB = (short*)alloc(4194304 * 2);
  short* KloB = (short*)alloc(4194304 * 2);
  short* Vb   = (short*)alloc(4194304 * 2);
  short* VtB  = (short*)alloc(4194304 * 2);
  short* pre  = (short*)alloc(4194304 * 2);
  float* rLbuf = (float*)alloc(65536 * 4);
  float* Thr   = (float*)alloc(65536 * 4);
  if (off > ws_size) return;

  k_convert<<<dim3(4096, 6), 256, 0, stream>>>(x, y, Wq, Wk, Wv, Wo,
                                               x16, y16, wq16, wk16, wv16, wohi);

  k_gemm_f16<1><<<256, 512, 0, stream>>>(x16, wq16, bq, QhiB, QloB, 4096, 1024, 1024);
  k_gemm_f16<1><<<256, 512, 0, stream>>>(y16, wk16, bk, KhiB, KloB, 4096, 1024, 1024);
  k_gemm_f16<0><<<256, 512, 0, stream>>>(y16, wv16, bv, Vb, nullptr, 4096, 1024, 1024);
  k_transpose_v<<<dim3(4, 64), 256, 0, stream>>>(Vb, VtB);
  k_mu<<<256, 256, 0, stream>>>(KhiB, KloB, QhiB, QloB, Thr);
  k_passA<<<1024, 256, 0, stream>>>(QhiB, KhiB, rLbuf);
  k_passB<<<1024, 256, 0, stream>>>(QhiB, QloB, KhiB, KloB, VtB, rLbuf, Thr, pre, rm);
  k_gemm_out<<<256, 512, 0, stream>>>(pre, wohi, bo, out, 4096, 1024, 1024);
}

// Round 9
// 177.939 us; speedup vs baseline: 1.5370x; 1.0546x over previous
//
#include <hip/hip_runtime.h>
#include <hip/hip_bf16.h>
#include <stdint.h>

typedef float f32x4 __attribute__((ext_vector_type(4)));
typedef short bf16x8 __attribute__((ext_vector_type(8)));
typedef _Float16 f16x8 __attribute__((ext_vector_type(8)));

#define DEV static __device__ __forceinline__

DEV float bf2f(short u) {
  union { float f; unsigned i; } v;
  v.i = ((unsigned)(unsigned short)u) << 16;
  return v.f;
}
DEV short f2bf(float f) {
  union { float f; unsigned i; } v;
  v.f = f;
  unsigned lsb = (v.i >> 16) & 1u;
  v.i += 0x7fffu + lsb;
  return (short)(v.i >> 16);
}
DEV short f2h(float f) {
  union { _Float16 h; short s; } u;
  u.h = (_Float16)f;
  return u.s;
}

DEV void glds16(const void* g, void* l) {
  __builtin_amdgcn_global_load_lds(
      (const __attribute__((address_space(1))) void*)g,
      (__attribute__((address_space(3))) void*)l, 16, 0, 0);
}

// ---------------------------------------------------------------------------
// Convert fp32 -> fp16 (x, y, Wq, Wk, Wv) and bf16 (Wo)
// ---------------------------------------------------------------------------
__global__ __launch_bounds__(256) void k_convert(
    const float* __restrict__ x, const float* __restrict__ y,
    const float* __restrict__ wq, const float* __restrict__ wk,
    const float* __restrict__ wv, const float* __restrict__ wo,
    short* __restrict__ x16, short* __restrict__ y16,
    short* __restrict__ wq16, short* __restrict__ wk16,
    short* __restrict__ wv16, short* __restrict__ wohi) {
  const float* src; short* dst; int n, half;
  switch (blockIdx.y) {
    case 0: src = x;  dst = x16;  n = 4194304; half = 1; break;
    case 1: src = y;  dst = y16;  n = 4194304; half = 1; break;
    case 2: src = wq; dst = wq16; n = 1048576; half = 1; break;
    case 3: src = wk; dst = wk16; n = 1048576; half = 1; break;
    case 4: src = wv; dst = wv16; n = 1048576; half = 1; break;
    default: src = wo; dst = wohi; n = 1048576; half = 0; break;
  }
  int i4 = blockIdx.x * 256 + threadIdx.x;
  if (i4 * 4 >= n) return;
  float4 v = ((const float4*)src)[i4];
  short4 h;
  float* pv = (float*)&v;
  short* ph = (short*)&h;
#pragma unroll
  for (int e = 0; e < 4; ++e) ph[e] = half ? f2h(pv[e]) : f2bf(pv[e]);
  ((short4*)dst)[i4] = h;
}

// ---------------------------------------------------------------------------
// XCD-pinned block remap for M=4096(32 row-panels) x N=1024(8 col-blocks)
// ---------------------------------------------------------------------------
DEV void gemm_block_map(int wg, long& bRow, long& bCol) {
  int rlow = wg & 7, c = (wg >> 3) & 7, rhigh = wg >> 6;
  bRow = (long)(rhigh * 8 + rlow) * 128;
  bCol = (long)c * 128;
}

// ---------------------------------------------------------------------------
// Plain bf16 NT GEMM with bias (Wo output projection).
// ---------------------------------------------------------------------------
__global__ __launch_bounds__(512) void k_gemm_out(
    const short* __restrict__ A, const short* __restrict__ B,
    const float* __restrict__ bias, float* __restrict__ C, int M, int N, int K) {
  __shared__ __align__(16) short As[128 * 64];
  __shared__ __align__(16) short Bs[128 * 64];
  const int tid = threadIdx.x, lane = tid & 63;
  const int w = tid >> 6, wr = w >> 1, wc = w & 1;
  const int lo = lane & 15, hi4 = lane >> 4;
  long bRow, bCol;
  gemm_block_map(blockIdx.x, bRow, bCol);
  f32x4 acc[2][4] = {};
  const int nks = K >> 6;
  for (int ks = 0; ks < nks; ++ks) {
#pragma unroll
    for (int i = 0; i < 2; ++i) {
      int c = i * 512 + tid;
      int r = c >> 3;
      int wi = ((c & 7) * 16) ^ ((r & 7) << 4);
      glds16((const char*)A + (bRow + r) * (long)(K * 2) + ks * 128 + wi, (char*)As + c * 16);
      glds16((const char*)B + (bCol + r) * (long)(K * 2) + ks * 128 + wi, (char*)Bs + c * 16);
    }
    __syncthreads();
#pragma unroll
    for (int kk = 0; kk < 2; ++kk) {
      bf16x8 af[2], bfr[4];
#pragma unroll
      for (int m = 0; m < 2; ++m) {
        int r = wr * 32 + m * 16 + lo;
        af[m] = *(const bf16x8*)((const char*)As + r * 128 + ((kk * 64 + hi4 * 16) ^ ((r & 7) << 4)));
      }
#pragma unroll
      for (int n = 0; n < 4; ++n) {
        int r = wc * 64 + n * 16 + lo;
        bfr[n] = *(const bf16x8*)((const char*)Bs + r * 128 + ((kk * 64 + hi4 * 16) ^ ((r & 7) << 4)));
      }
#pragma unroll
      for (int m = 0; m < 2; ++m)
#pragma unroll
        for (int n = 0; n < 4; ++n)
          acc[m][n] = __builtin_amdgcn_mfma_f32_16x16x32_bf16(af[m], bfr[n], acc[m][n], 0, 0, 0);
    }
    __syncthreads();
  }
#pragma unroll
  for (int n = 0; n < 4; ++n) {
    long col = bCol + wc * 64 + n * 16 + lo;
    float bv = bias[col];
#pragma unroll
    for (int m = 0; m < 2; ++m) {
      long row0 = bRow + wr * 32 + m * 16 + hi4 * 4;
#pragma unroll
      for (int j = 0; j < 4; ++j)
        C[(row0 + j) * N + col] = acc[m][n][j] + bv;
    }
  }
}

// ---------------------------------------------------------------------------
// fp16 NT GEMM with bias. OUT_MODE=2: fp16 output (Q/K projections).
// OUT_MODE=0: bf16 output (V projection).
// ---------------------------------------------------------------------------
template <int OUT_MODE>
__global__ __launch_bounds__(512) void k_gemm_f16(
    const short* __restrict__ A, const short* __restrict__ B,
    const float* __restrict__ bias, short* __restrict__ C, int M, int N, int K) {
  __shared__ __align__(16) short As[128 * 64];
  __shared__ __align__(16) short Bs[128 * 64];
  const int tid = threadIdx.x, lane = tid & 63;
  const int w = tid >> 6, wr = w >> 1, wc = w & 1;
  const int lo = lane & 15, hi4 = lane >> 4;
  long bRow, bCol;
  gemm_block_map(blockIdx.x, bRow, bCol);
  f32x4 acc[2][4] = {};
  const int nks = K >> 6;
  for (int ks = 0; ks < nks; ++ks) {
#pragma unroll
    for (int i = 0; i < 2; ++i) {
      int c = i * 512 + tid;
      int r = c >> 3;
      int wi = ((c & 7) * 16) ^ ((r & 7) << 4);
      glds16((const char*)A + (bRow + r) * (long)(K * 2) + ks * 128 + wi, (char*)As + c * 16);
      glds16((const char*)B + (bCol + r) * (long)(K * 2) + ks * 128 + wi, (char*)Bs + c * 16);
    }
    __syncthreads();
#pragma unroll
    for (int kk = 0; kk < 2; ++kk) {
      f16x8 af[2], bfr[4];
#pragma unroll
      for (int m = 0; m < 2; ++m) {
        int r = wr * 32 + m * 16 + lo;
        af[m] = *(const f16x8*)((const char*)As + r * 128 + ((kk * 64 + hi4 * 16) ^ ((r & 7) << 4)));
      }
#pragma unroll
      for (int n = 0; n < 4; ++n) {
        int r = wc * 64 + n * 16 + lo;
        bfr[n] = *(const f16x8*)((const char*)Bs + r * 128 + ((kk * 64 + hi4 * 16) ^ ((r & 7) << 4)));
      }
#pragma unroll
      for (int m = 0; m < 2; ++m)
#pragma unroll
        for (int n = 0; n < 4; ++n)
          acc[m][n] = __builtin_amdgcn_mfma_f32_16x16x32_f16(af[m], bfr[n], acc[m][n], 0, 0, 0);
    }
    __syncthreads();
  }
#pragma unroll
  for (int n = 0; n < 4; ++n) {
    long col = bCol + wc * 64 + n * 16 + lo;
    float bv = bias[col];
#pragma unroll
    for (int m = 0; m < 2; ++m)
#pragma unroll
      for (int j = 0; j < 4; ++j) {
        long row = bRow + wr * 32 + m * 16 + hi4 * 4 + j;
        float v = acc[m][n][j] + bv;
        C[row * N + col] = (OUT_MODE == 2) ? f2h(v) : f2bf(v);
      }
  }
}

// ---------------------------------------------------------------------------
// Transpose V slices: Vb flat [g][1024 t][64 d] -> Vt [g][64 d][1024 t]
// ---------------------------------------------------------------------------
__global__ __launch_bounds__(256) void k_transpose_v(const short* __restrict__ Vb,
                                                     short* __restrict__ Vt) {
  __shared__ __align__(16) short T[64][264];
  int g = blockIdx.y, t0 = blockIdx.x * 256;
  int tid = threadIdx.x;
  const short* src = Vb + (long)g * 65536;
#pragma unroll
  for (int i = 0; i < 8; ++i) {
    int c = i * 256 + tid;
    int t = c >> 3, dc = (c & 7) * 8;
    bf16x8 v = *(const bf16x8*)(src + (long)(t0 + t) * 64 + dc);
#pragma unroll
    for (int e = 0; e < 8; ++e) T[dc + e][t] = v[e];
  }
  __syncthreads();
  short* dst = Vt + (long)g * 65536;
#pragma unroll
  for (int i = 0; i < 8; ++i) {
    int c = i * 256 + tid;
    int d = c >> 5, tc = (c & 31) * 8;
    bf16x8 v = *(const bf16x8*)(&T[d][tc]);
    *(bf16x8*)(dst + (long)d * 1024 + t0 + tc) = v;
  }
}

// ---------------------------------------------------------------------------
// k_mu: Thr[g,s] = (q_s . sum_t k_t) * NORM / 1024.  4 blocks per slice.
// fp16 single-buffer inputs.
// ---------------------------------------------------------------------------
__global__ __launch_bounds__(256) void k_mu(
    const short* __restrict__ K16, const short* __restrict__ Q16,
    float* __restrict__ Thr) {
  __shared__ float tmp[32][64];
  __shared__ float ksum[64];
  const int g = blockIdx.x >> 2, q = blockIdx.x & 3;
  const int tid = threadIdx.x;
  const int d8 = tid & 7, tq = tid >> 3;
  const short* kp = K16 + (long)g * 65536;
  float acc[8] = {};
  for (int t = tq; t < 1024; t += 32) {
    f16x8 a = *(const f16x8*)(kp + t * 64 + d8 * 8);
#pragma unroll
    for (int e = 0; e < 8; ++e) acc[e] += (float)a[e];
  }
#pragma unroll
  for (int e = 0; e < 8; ++e) tmp[tq][d8 * 8 + e] = acc[e];
  __syncthreads();
  if (tid < 64) {
    float s = 0.f;
#pragma unroll
    for (int qq = 0; qq < 32; ++qq) s += tmp[qq][tid];
    ksum[tid] = s;
  }
  __syncthreads();
  const float c = 0.03125f / 1024.f;
  const int s = q * 256 + tid;
  const short* qp = Q16 + (long)g * 65536 + s * 64;
  float dot = 0.f;
#pragma unroll
  for (int d0 = 0; d0 < 64; d0 += 8) {
    f16x8 a = *(const f16x8*)(qp + d0);
#pragma unroll
    for (int e = 0; e < 8; ++e) dot += (float)a[e] * ksum[d0 + e];
  }
  Thr[g * 1024 + s] = dot * c;
}

// ---------------------------------------------------------------------------
// Pass A (fp16 1-term): block owns 64 columns t; iterates Q tiles.
// rL[t] = 1 / sum_s exp2(S*CEXP) -- same e's as passB (consistent).
// ---------------------------------------------------------------------------
__global__ __launch_bounds__(256) void k_passA(
    const short* __restrict__ Q16, const short* __restrict__ K16,
    float* __restrict__ rL) {
  __shared__ __align__(16) short Ks[64 * 64];
  __shared__ __align__(16) short Qs[64 * 64];
  const int wg = blockIdx.x;
  const int g = (wg & 7) | ((wg >> 7) << 3);
  const int tb = (wg >> 3) & 15;
  const int tid = threadIdx.x, lane = tid & 63;
  const int w = tid >> 6;
  const int lo = lane & 15, hi4 = lane >> 4;
  const long gbase = (long)g * 131072;
  const float CEXP = 0.045136860026163146f;  // 2^-5 * log2(e)
#pragma unroll
  for (int i = 0; i < 2; ++i) {
    int c = i * 256 + tid;
    int r = c >> 3;
    int wi = ((c & 7) * 16) ^ ((r & 7) << 4);
    glds16((const char*)K16 + gbase + (long)(tb * 64 + r) * 128 + wi, (char*)Ks + c * 16);
  }
  __syncthreads();
  f16x8 kf[2];
#pragma unroll
  for (int kk = 0; kk < 2; ++kk) {
    int r = w * 16 + lo;
    kf[kk] = *(const f16x8*)((const char*)Ks + r * 128 + ((kk * 64 + hi4 * 16) ^ ((r & 7) << 4)));
  }
  float Lacc[4] = {};
  for (int sb = 0; sb < 16; ++sb) {
#pragma unroll
    for (int i = 0; i < 2; ++i) {
      int c = i * 256 + tid;
      int r = c >> 3;
      int wi = ((c & 7) * 16) ^ ((r & 7) << 4);
      glds16((const char*)Q16 + gbase + (long)(sb * 64 + r) * 128 + wi, (char*)Qs + c * 16);
    }
    __syncthreads();
    f32x4 s[4] = {};
#pragma unroll
    for (int kk = 0; kk < 2; ++kk) {
#pragma unroll
      for (int n = 0; n < 4; ++n) {
        int r = n * 16 + lo;
        f16x8 qf = *(const f16x8*)((const char*)Qs + r * 128 +
                                   ((kk * 64 + hi4 * 16) ^ ((r & 7) << 4)));
        __builtin_amdgcn_s_setprio(1);
        s[n] = __builtin_amdgcn_mfma_f32_16x16x32_f16(kf[kk], qf, s[n], 0, 0, 0);
        __builtin_amdgcn_s_setprio(0);
      }
    }
#pragma unroll
    for (int n = 0; n < 4; ++n)
#pragma unroll
      for (int j = 0; j < 4; ++j)
        Lacc[j] += __builtin_amdgcn_exp2f(s[n][j] * CEXP);
    __syncthreads();
  }
#pragma unroll
  for (int j = 0; j < 4; ++j) {
    float v = Lacc[j];
    v += __shfl_xor(v, 1);
    v += __shfl_xor(v, 2);
    v += __shfl_xor(v, 4);
    v += __shfl_xor(v, 8);
    if (lo == 0) rL[g * 1024 + tb * 64 + w * 16 + hi4 * 4 + j] = 1.0f / v;
  }
}

// ---------------------------------------------------------------------------
// Pass B: S^T via swapped-operand 1-term fp16 MFMA (Q/K are fp16-exact).
// LDS 32 KB -> 5 blocks/CU. Softmax/P-store/PV identical to round 8.
// ---------------------------------------------------------------------------
__global__ __launch_bounds__(256, 5) void k_passB(
    const short* __restrict__ Q16, const short* __restrict__ K16,
    const short* __restrict__ Vt, const float* __restrict__ rL,
    const float* __restrict__ Thr, short* __restrict__ Pre,
    const int* __restrict__ rmask) {
  __shared__ __align__(16) short Ks[64 * 64];
  __shared__ __align__(16) short Vs[64 * 64];
  __shared__ __align__(16) short Ps1[64 * 64], Ps2[64 * 64];
  const int wg = blockIdx.x;
  const int g = (wg & 7) | ((wg >> 7) << 3);
  const int rb = (wg >> 3) & 15;
  const int tid = threadIdx.x, lane = tid & 63;
  const int w = tid >> 6;
  const int lo = lane & 15, hi4 = lane >> 4;
  const long gbase = (long)g * 131072;
  const bool use_mask = (*rmask != 0);
  const int srow = w * 16 + lo;
  f16x8 qf[2];
  {
    const char* qr = (const char*)Q16 + gbase + (long)(rb * 64 + srow) * 128;
#pragma unroll
    for (int kk = 0; kk < 2; ++kk)
      qf[kk] = *(const f16x8*)(qr + kk * 64 + hi4 * 16);
  }
  const float thre32 = use_mask ? Thr[g * 1024 + rb * 64 + srow] * 32.0f : -3.4e38f;
  const float CEXP = 0.045136860026163146f;  // 2^-5 * log2(e)
  float rpart = 0.f, zpart = 0.f;
  f32x4 o1[4] = {}, o2[4] = {};

  for (int tb = 0; tb < 16; ++tb) {
#pragma unroll
    for (int i = 0; i < 2; ++i) {
      int c = i * 256 + tid;
      int r = c >> 3;
      int wi = ((c & 7) * 16) ^ ((r & 7) << 4);
      glds16((const char*)K16 + gbase + (long)(tb * 64 + r) * 128 + wi, (char*)Ks + c * 16);
      glds16((const char*)Vt + gbase + (long)r * 2048 + tb * 128 + wi, (char*)Vs + c * 16);
    }
    __syncthreads();
    // --- S^T = K.Q^T (1-term fp16, 8 MFMA/wave) ---
    f32x4 s[4] = {};
#pragma unroll
    for (int kk = 0; kk < 2; ++kk) {
#pragma unroll
      for (int n = 0; n < 4; ++n) {
        int r = n * 16 + lo;
        f16x8 kf = *(const f16x8*)((const char*)Ks + r * 128 +
                                   ((kk * 64 + hi4 * 16) ^ ((r & 7) << 4)));
        __builtin_amdgcn_s_setprio(1);
        s[n] = __builtin_amdgcn_mfma_f32_16x16x32_f16(kf, qf[kk], s[n], 0, 0, 0);
        __builtin_amdgcn_s_setprio(0);
      }
    }
    // --- softmax pieces + dual P-store ---
#pragma unroll
    for (int n = 0; n < 4; ++n) {
      const float4 rl4 = *(const float4*)(rL + g * 1024 + tb * 64 + n * 16 + hi4 * 4);
      const float* rlp = (const float*)&rl4;
      float p1v[4], p2v[4];
#pragma unroll
      for (int j = 0; j < 4; ++j) {
        float sraw = s[n][j];
        float e = __builtin_amdgcn_exp2f(sraw * CEXP);
        float p1 = e * rlp[j];
        float p2 = (sraw > thre32) ? e : 0.f;
        p1v[j] = p1;
        p2v[j] = p2;
        rpart += p1;
        zpart += p2;
      }
      unsigned u10, u11, u20, u21;
      asm("v_cvt_pk_bf16_f32 %0, %1, %2" : "=v"(u10) : "v"(p1v[0]), "v"(p1v[1]));
      asm("v_cvt_pk_bf16_f32 %0, %1, %2" : "=v"(u11) : "v"(p1v[2]), "v"(p1v[3]));
      asm("v_cvt_pk_bf16_f32 %0, %1, %2" : "=v"(u20) : "v"(p2v[0]), "v"(p2v[1]));
      asm("v_cvt_pk_bf16_f32 %0, %1, %2" : "=v"(u21) : "v"(p2v[2]), "v"(p2v[3]));
      int colb = n * 32 + hi4 * 8;
      int boff = srow * 128 + (colb ^ ((srow & 7) << 4));
      uint2 w1; w1.x = u10; w1.y = u11;
      uint2 w2; w2.x = u20; w2.y = u21;
      *(uint2*)((char*)Ps1 + boff) = w1;
      *(uint2*)((char*)Ps2 + boff) = w2;
    }
    // no barrier: each wave reads back only its own 16 P rows (intra-wave)
#pragma unroll
    for (int kk = 0; kk < 2; ++kk) {
      int poff = srow * 128 + ((kk * 64 + hi4 * 16) ^ ((srow & 7) << 4));
      bf16x8 pa1 = *(const bf16x8*)((const char*)Ps1 + poff);
      bf16x8 pa2 = *(const bf16x8*)((const char*)Ps2 + poff);
#pragma unroll
      for (int n = 0; n < 4; ++n) {
        int d = n * 16 + lo;
        bf16x8 vb = *(const bf16x8*)((const char*)Vs + d * 128 +
                                     ((kk * 64 + hi4 * 16) ^ ((d & 7) << 4)));
        __builtin_amdgcn_s_setprio(1);
        o1[n] = __builtin_amdgcn_mfma_f32_16x16x32_bf16(pa1, vb, o1[n], 0, 0, 0);
        o2[n] = __builtin_amdgcn_mfma_f32_16x16x32_bf16(pa2, vb, o2[n], 0, 0, 0);
        __builtin_amdgcn_s_setprio(0);
      }
    }
    __syncthreads();
  }
  float r = rpart;
  r += __shfl_xor(r, 16);
  r += __shfl_xor(r, 32);
  float z = zpart;
  z += __shfl_xor(z, 16);
  z += __shfl_xor(z, 32);
  float* Rbuf = (float*)Ps1;
  float* Zbuf = (float*)Ps2;
  if (hi4 == 0) { Rbuf[srow] = r; Zbuf[srow] = z; }
  __syncthreads();
#pragma unroll
  for (int n = 0; n < 4; ++n)
#pragma unroll
    for (int j = 0; j < 4; ++j) {
      int rl_ = w * 16 + hi4 * 4 + j;
      float rr = fmaxf(Rbuf[rl_], 1e-12f);
      float zz = fmaxf(Zbuf[rl_], 1e-30f);
      float val = 0.5f * (o1[n][j] / rr + o2[n][j] / zz);
      Pre[(long)g * 65536 + (long)(rb * 64 + rl_) * 64 + n * 16 + lo] = f2bf(val);
    }
}

// ---------------------------------------------------------------------------
extern "C" void kernel_launch(void* const* d_in, const int* in_sizes, int n_in,
                              void* d_out, int out_size, void* d_ws, size_t ws_size,
                              hipStream_t stream) {
  const float* x  = (const float*)d_in[0];
  const float* y  = (const float*)d_in[1];
  const float* Wq = (const float*)d_in[2];
  const float* bq = (const float*)d_in[3];
  const float* Wk = (const float*)d_in[4];
  const float* bk = (const float*)d_in[5];
  const float* Wv = (const float*)d_in[6];
  const float* bv = (const float*)d_in[7];
  const float* Wo = (const float*)d_in[8];
  const float* bo = (const float*)d_in[9];
  const int* rm   = (const int*)d_in[10];
  float* out = (float*)d_out;

  char* ws = (char*)d_ws;
  size_t off = 0;
  auto alloc = [&](size_t bytes) {
    char* p = ws + off;
    off += (bytes + 255) & ~(size_t)255;
    return p;
  };
  short* x16  = (short*)alloc(4194304 * 2);
  short* y16  = (short*)alloc(4194304 * 2);
  short* wq16 = (short*)alloc(1048576 * 2);
  short* wk16 = (short*)alloc(1048576 * 2);
  short* wv16 = (short*)alloc(1048576 * 2);
  short* wohi = (short*)alloc(1048576 * 2);
  short* Q16  = (short*)alloc(4194304 * 2);
  short* K16  = (short*)alloc(4194304 * 2);
  short* Vb   = (short*)alloc(4194304 * 2);
  short* VtB  = (short*)alloc(4194304 * 2);
  short* pre  = (short*)alloc(4194304 * 2);
  float* rLbuf = (float*)alloc(65536 * 4);
  float* Thr   = (float*)alloc(65536 * 4);
  if (off > ws_size) return;

  k_convert<<<dim3(4096, 6), 256, 0, stream>>>(x, y, Wq, Wk, Wv, Wo,
                                               x16, y16, wq16, wk16, wv16, wohi);

  k_gemm_f16<2><<<256, 512, 0, stream>>>(x16, wq16, bq, Q16, 4096, 1024, 1024);
  k_gemm_f16<2><<<256, 512, 0, stream>>>(y16, wk16, bk, K16, 4096, 1024, 1024);
  k_gemm_f16<0><<<256, 512, 0, stream>>>(y16, wv16, bv, Vb, 4096, 1024, 1024);
  k_transpose_v<<<dim3(4, 64), 256, 0, stream>>>(Vb, VtB);
  k_mu<<<256, 256, 0, stream>>>(K16, Q16, Thr);
  k_passA<<<1024, 256, 0, stream>>>(Q16, K16, rLbuf);
  k_passB<<<1024, 256, 0, stream>>>(Q16, K16, VtB, rLbuf, Thr, pre, rm);
  k_gemm_out<<<256, 512, 0, stream>>>(pre, wohi, bo, out, 4096, 1024, 1024);
}